// Round 6
// baseline (276.983 us; speedup 1.0000x reference)
//
#include <hip/hip_runtime.h>
#include <hip/hip_bf16.h>
#include <stdint.h>

// ---------------------------------------------------------------------------
// SplitCausalSelfAttention on MI355X (gfx950), bf16 MFMA implementation.
// B=4, T=2048, C=1024, H=16, D=64.
// R17: joint-pass attention.  Block (jj,bh) previously ran TWO passes
//      (qt=jj then qt=31-jj), staging 33 K/V tiles; the second pass
//      re-staged rows the first already streamed.  Now ONE K/V stream
//      st=0..31-jj (avg 24.5 stages, -26%): Q-tile B (qt=31-jj) always
//      active, Q-tile A (qt=jj) active while st<=jj (block-uniform
//      branch).  MFMA per stage x1.33 avg.  VGPR fit: o/l/qf doubled
//      (+28) paid for by compacting koff/voff (sr&7==l15&7 folds the
//      sblk term into the ds_read immediate; 24 regs -> 6).  Epilogue
//      transposes A then B through the same wave-private LDS buffer.
//      qkv (mix512)/proj/cast unchanged from R16 for attribution.
// ---------------------------------------------------------------------------

typedef unsigned short u16;
typedef __attribute__((ext_vector_type(8))) __bf16 bf16x8;  // 4 VGPRs (A/B frag, K=32)
typedef __attribute__((ext_vector_type(4))) float  f32x4;   // C/D frag
typedef __attribute__((ext_vector_type(4))) unsigned short u16x4;
typedef __attribute__((ext_vector_type(8))) unsigned short u16x8;
typedef __attribute__((ext_vector_type(4))) short s16x4;    // 2 VGPRs (A/B frag, K=16)

#define B_  4
#define T_  2048
#define C_  1024
#define H_  16
#define D_  64
#define BT_ (B_ * T_)
#define NT_ 16        // K-tiles of 64 over K=1024

// scale = 1/sqrt(D) folded with log2(e) so softmax uses exp2
#define Q_SCALE 0.1803368801111204f

__device__ __forceinline__ u16 f32_to_bf16(float f) {
    unsigned int u = __float_as_uint(f);
    unsigned int r = (u + 0x7FFFu + ((u >> 16) & 1u)) >> 16;
    return (u16)r;
}

__device__ __forceinline__ unsigned int pk_bf16(float a, float b) {
    float2 f2; f2.x = a; f2.y = b;
    __hip_bfloat162 h = __float22bfloat162_rn(f2);
    return *(unsigned int*)&h;
}

__device__ __forceinline__ void async16(const void* g, void* lds) {
    __builtin_amdgcn_global_load_lds(
        (const __attribute__((address_space(1))) void*)g,
        (__attribute__((address_space(3))) void*)lds, 16, 0, 0);
}

// ---------------------------------------------------------------------------
// single cast kernel: X (8192 blocks) + 4 weights (1024 blocks each)
// ---------------------------------------------------------------------------
__global__ void cast_all_kernel(const float* __restrict__ X,
                                const float* __restrict__ w0, const float* __restrict__ w1,
                                const float* __restrict__ w2, const float* __restrict__ w3,
                                u16* __restrict__ xo,
                                u16* __restrict__ o0, u16* __restrict__ o1,
                                u16* __restrict__ o2, u16* __restrict__ o3) {
    int id = blockIdx.x;
    const float* in; u16* out; int i;
    if (id < 8192) {
        in = X; out = xo; i = id * 256 + threadIdx.x;
    } else {
        int k = (id - 8192) >> 10;
        in  = (k == 0) ? w0 : (k == 1) ? w1 : (k == 2) ? w2 : w3;
        out = (k == 0) ? o0 : (k == 1) ? o1 : (k == 2) ? o2 : o3;
        i = ((id - 8192) & 1023) * 256 + threadIdx.x;
    }
    float4 v = ((const float4*)in)[i];
    u16x4 o;
    o[0] = f32_to_bf16(v.x); o[1] = f32_to_bf16(v.y);
    o[2] = f32_to_bf16(v.z); o[3] = f32_to_bf16(v.w);
    ((u16x4*)out)[i] = o;
}

// ---------------------------------------------------------------------------
// Full-tile 256x256 4-phase core (R13, non-swap only).
// ---------------------------------------------------------------------------
#define QPHASE(CB, MH, NH, DOISSUE, G, GATE)                                      \
  {                                                                               \
    if ((NH) == 0) {                                                              \
      _Pragma("unroll")                                                           \
      for (int f = 0; f < 4; ++f) {                                               \
        _Pragma("unroll")                                                         \
        for (int ks = 0; ks < 2; ++ks)                                            \
          xf[f][ks] = *(const bf16x8*)((CB) + (MH) * 16384 + axoff[f][ks]);       \
      }                                                                           \
    }                                                                             \
    if ((MH) == 0) {                                                              \
      _Pragma("unroll")                                                           \
      for (int e = 0; e < 2; ++e) {                                               \
        _Pragma("unroll")                                                         \
        for (int ks = 0; ks < 2; ++ks)                                            \
          wf[NH][e][ks] = *(const bf16x8*)((CB) + (NH) * 16384 + bwoff[e][ks]);   \
      }                                                                           \
    }                                                                             \
    if (DOISSUE) issue_unit(G);                                                   \
    if ((GATE) == 4)      asm volatile("s_waitcnt vmcnt(4)" ::: "memory");        \
    else if ((GATE) == 2) asm volatile("s_waitcnt vmcnt(2)" ::: "memory");        \
    else if ((GATE) == 0) asm volatile("s_waitcnt vmcnt(0)" ::: "memory");        \
    __builtin_amdgcn_s_barrier();                                                 \
    asm volatile("" ::: "memory");                                                \
    __builtin_amdgcn_s_setprio(1);                                                \
    _Pragma("unroll")                                                             \
    for (int f = 0; f < 4; ++f) {                                                 \
      _Pragma("unroll")                                                           \
      for (int e = 0; e < 2; ++e) {                                               \
        f32x4 a_ = acc[(MH) * 4 + f][(NH) * 2 + e];                               \
        a_ = __builtin_amdgcn_mfma_f32_16x16x32_bf16(wf[NH][e][0], xf[f][0], a_, 0, 0, 0); \
        a_ = __builtin_amdgcn_mfma_f32_16x16x32_bf16(wf[NH][e][1], xf[f][1], a_, 0, 0, 0); \
        acc[(MH) * 4 + f][(NH) * 2 + e] = a_;                                     \
      }                                                                           \
    }                                                                             \
    __builtin_amdgcn_s_setprio(0);                                                \
    asm volatile("" ::: "memory");                                                \
    __builtin_amdgcn_s_barrier();                                                 \
    asm volatile("" ::: "memory");                                                \
  }

__device__ __forceinline__ void qkv256_core(const u16* __restrict__ Arow,
                                            const u16* __restrict__ Brow,
                                            char* lds, f32x4 (&acc)[8][4])
{
    int tid = threadIdx.x, lane = tid & 63, w = tid >> 6;
    int quad = lane >> 4, l15 = lane & 15;
    int wm = w >> 2, wn = w & 3;

    int gc = (((tid & 7) - (tid >> 3)) & 7) * 8;
    const u16* xsrc0 = Arow + (size_t)(tid >> 3) * C_ + gc;
    const u16* xsrc1 = xsrc0 + (size_t)64 * C_;
    const u16* wsrc0 = Brow + (size_t)(tid >> 3) * C_ + gc;
    const u16* wsrc1 = wsrc0 + (size_t)64 * C_;

    auto issue_unit = [&](int g) {
        int u = g & 3, kt = g >> 2;
        char* d = lds + ((kt & 1) << 16) + (u << 14) + (w << 10);
        size_t off = (size_t)(u & 1) * (128 * C_) + (size_t)kt * 64;
        const u16* s0 = (u < 2) ? xsrc0 : wsrc0;
        const u16* s1 = (u < 2) ? xsrc1 : wsrc1;
        async16(s0 + off, d);
        async16(s1 + off, d + 8192);
    };

    int axoff[4][2], bwoff[2][2];
#pragma unroll
    for (int f = 0; f < 4; ++f) {
        int r = wm * 64 + f * 16 + l15;
#pragma unroll
        for (int ks = 0; ks < 2; ++ks)
            axoff[f][ks] = r * 128 + (((ks * 4 + quad + r) & 7) << 4);
    }
#pragma unroll
    for (int e = 0; e < 2; ++e) {
        int r = wn * 32 + e * 16 + l15;
#pragma unroll
        for (int ks = 0; ks < 2; ++ks)
            bwoff[e][ks] = 32768 + r * 128 + (((ks * 4 + quad + r) & 7) << 4);
    }

    bf16x8 xf[4][2];       // A-frags for current mh (read at nh==0 phases)
    bf16x8 wf[2][2][2];    // B-frags for both nh (read at mh==0 phases)

    issue_unit(0); issue_unit(2); issue_unit(3); issue_unit(1);
    asm volatile("s_waitcnt vmcnt(4)" ::: "memory");
    __builtin_amdgcn_s_barrier();
    asm volatile("" ::: "memory");

    for (int t = 0; t < NT_ - 1; ++t) {
        char* cb = lds + ((t & 1) << 16);
        int g4 = (t + 1) << 2;
        QPHASE(cb, 0, 0, 1, g4 + 0, 4);    // reads u0,u2; issue next.u0
        QPHASE(cb, 0, 1, 1, g4 + 2, 4);    // reads u3;    issue next.u2
        QPHASE(cb, 1, 0, 1, g4 + 3, -1);   // reads u1;    issue next.u3
        QPHASE(cb, 1, 1, 1, g4 + 1, 4);    // pure reg;    issue next.u1
    }
    {   // peeled last tile (15, odd -> dbuf 1): tail drain 2 -> 0
        char* cb = lds + 65536;
        QPHASE(cb, 0, 0, 0, 0, 2);
        QPHASE(cb, 0, 1, 0, 0, 0);
        QPHASE(cb, 1, 0, 0, 0, -1);
        QPHASE(cb, 1, 1, 0, 0, -1);
    }
}

// ---------------------------------------------------------------------------
// Half-tile 128x256 core (V panels, swapped operands).  (R16)
// ---------------------------------------------------------------------------
__device__ __forceinline__ void qkv128v_core(const u16* __restrict__ Arow,
                                             const u16* __restrict__ Brow,
                                             char* lds, f32x4 (&acc)[4][4])
{
    int tid = threadIdx.x, lane = tid & 63, w = tid >> 6;
    int quad = lane >> 4, l15 = lane & 15;
    int wm = w >> 2, wn = w & 3;

    int gc = (((tid & 7) - (tid >> 3)) & 7) * 8;
    const u16* asrc  = Arow + (size_t)(tid >> 3) * C_ + gc;
    const u16* bsrc0 = Brow + (size_t)(tid >> 3) * C_ + gc;
    const u16* bsrc1 = bsrc0 + (size_t)64 * C_;

    auto issue3 = [&](int kt) {
        char* db = lds + ((kt & 1) << 16) + (w << 10);
        int ko = kt * 64;
        async16(asrc + ko,                       db);
        async16(asrc + ko + (size_t)64 * C_,     db + 8192);
        async16(bsrc0 + ko,                      db + 32768);
        async16(bsrc1 + ko,                      db + 32768 + 8192);
        async16(bsrc0 + ko + (size_t)128 * C_,   db + 49152);
        async16(bsrc1 + ko + (size_t)128 * C_,   db + 49152 + 8192);
    };

    int axoff[4][2], bwoff[2][2];
#pragma unroll
    for (int f = 0; f < 4; ++f) {
        int r = wm * 64 + f * 16 + l15;
#pragma unroll
        for (int ks = 0; ks < 2; ++ks)
            axoff[f][ks] = r * 128 + (((ks * 4 + quad + r) & 7) << 4);
    }
#pragma unroll
    for (int e = 0; e < 2; ++e) {
        int r = wn * 32 + e * 16 + l15;
#pragma unroll
        for (int ks = 0; ks < 2; ++ks)
            bwoff[e][ks] = 32768 + r * 128 + (((ks * 4 + quad + r) & 7) << 4);
    }

    bf16x8 xf[4][2], wf[2][2];

    issue3(0);

    for (int t = 0; t < NT_; ++t) {
        char* cb = lds + ((t & 1) << 16);
        if (t + 1 < NT_) issue3(t + 1);
        if (t == NT_ - 1) asm volatile("s_waitcnt vmcnt(0)" ::: "memory");
        else              asm volatile("s_waitcnt vmcnt(6)" ::: "memory");
        __builtin_amdgcn_s_barrier();
        asm volatile("" ::: "memory");

#pragma unroll
        for (int f = 0; f < 4; ++f)
#pragma unroll
            for (int ks = 0; ks < 2; ++ks)
                xf[f][ks] = *(const bf16x8*)(cb + axoff[f][ks]);
#pragma unroll
        for (int e = 0; e < 2; ++e)
#pragma unroll
            for (int ks = 0; ks < 2; ++ks)
                wf[e][ks] = *(const bf16x8*)(cb + bwoff[e][ks]);
        __builtin_amdgcn_s_setprio(1);
#pragma unroll
        for (int f = 0; f < 4; ++f)
#pragma unroll
            for (int e = 0; e < 2; ++e) {
                f32x4 a_ = acc[f][e];
                a_ = __builtin_amdgcn_mfma_f32_16x16x32_bf16(xf[f][0], wf[e][0], a_, 0, 0, 0);
                a_ = __builtin_amdgcn_mfma_f32_16x16x32_bf16(xf[f][1], wf[e][1], a_, 0, 0, 0);
                acc[f][e] = a_;
            }
        __builtin_amdgcn_s_setprio(0);

#pragma unroll
        for (int e = 0; e < 2; ++e)
#pragma unroll
            for (int ks = 0; ks < 2; ++ks)
                wf[e][ks] = *(const bf16x8*)(cb + 16384 + bwoff[e][ks]);
        __builtin_amdgcn_s_setprio(1);
#pragma unroll
        for (int f = 0; f < 4; ++f)
#pragma unroll
            for (int e = 0; e < 2; ++e) {
                f32x4 a_ = acc[f][2 + e];
                a_ = __builtin_amdgcn_mfma_f32_16x16x32_bf16(xf[f][0], wf[e][0], a_, 0, 0, 0);
                a_ = __builtin_amdgcn_mfma_f32_16x16x32_bf16(xf[f][1], wf[e][1], a_, 0, 0, 0);
                acc[f][2 + e] = a_;
            }
        __builtin_amdgcn_s_setprio(0);
        asm volatile("" ::: "memory");
        __builtin_amdgcn_s_barrier();
        asm volatile("" ::: "memory");
    }
}

// ---------------------------------------------------------------------------
// Fused QKV, mixed grid 512 (R16).
// ---------------------------------------------------------------------------
__global__ __launch_bounds__(512, 2) void qkv_mix512(
    const u16* __restrict__ Xb, const u16* __restrict__ Wcat,
    u16* __restrict__ Qb, u16* __restrict__ Kb, u16* __restrict__ Vtb)
{
    __shared__ __attribute__((aligned(128))) char LDSRAW[131072];

    int id = blockIdx.x;
    int tid = threadIdx.x, lane = tid & 63, w = tid >> 6;
    int quad = lane >> 4, l15 = lane & 15;
    int wm = w >> 2, wn = w & 3;

    if (id < 256) {
        int ti = (id & 7) * 32 + (id >> 3);
        int bm = ti & 31, bn = ti >> 5;
        int m0 = bm * 256, chb = bn * 256;

        f32x4 acc[8][4];
        const f32x4 z4 = {0.f, 0.f, 0.f, 0.f};
#pragma unroll
        for (int i = 0; i < 8; ++i)
#pragma unroll
            for (int j = 0; j < 4; ++j) acc[i][j] = z4;

        qkv256_core(Xb + (size_t)m0 * C_, Wcat + (size_t)chb * C_, LDSRAW, acc);

#pragma unroll
        for (int mi = 0; mi < 8; ++mi) {
            size_t trow = (size_t)(m0 + (mi >> 2) * 128 + wm * 64 + (mi & 3) * 16 + l15) * C_;
#pragma unroll
            for (int nj = 0; nj < 4; ++nj) {
                int colb = chb + (nj >> 1) * 128 + wn * 32 + (nj & 1) * 16 + quad * 4;
                u16* OUT = (colb < 1024) ? Qb : Kb;
                float sc = (colb < 1024) ? Q_SCALE : 1.0f;
                u16x4 v;
#pragma unroll
                for (int rr = 0; rr < 4; ++rr) v[rr] = f32_to_bf16(acc[mi][nj][rr] * sc);
                *(u16x4*)&OUT[trow + (colb & 1023)] = v;
            }
        }
    } else {
        int id2 = id - 256;
        int hw = (id2 & 7) * 32 + (id2 >> 3);
        int vt = hw >> 6;
        int bm = (hw & 63) >> 1, half = hw & 1;
        int m0h = bm * 256 + half * 128;
        int chb = 2048 + vt * 256;

        f32x4 acc[4][4];
        const f32x4 z4 = {0.f, 0.f, 0.f, 0.f};
#pragma unroll
        for (int i = 0; i < 4; ++i)
#pragma unroll
            for (int j = 0; j < 4; ++j) acc[i][j] = z4;

        qkv128v_core(Xb + (size_t)m0h * C_, Wcat + (size_t)chb * C_, LDSRAW, acc);

#pragma unroll
        for (int mi = 0; mi < 4; ++mi) {
            int t0 = m0h + wm * 64 + mi * 16 + quad * 4;
            int b_ = t0 >> 11, tl = t0 & (T_ - 1);
#pragma unroll
            for (int nj = 0; nj < 4; ++nj) {
                int ch = chb + (nj >> 1) * 128 + wn * 32 + (nj & 1) * 16 + l15;
                int h = (ch >> 6) & 15, d = ch & 63;
                u16x4 v;
#pragma unroll
                for (int rr = 0; rr < 4; ++rr) v[rr] = f32_to_bf16(acc[mi][nj][rr]);
                *(u16x4*)&Vtb[((size_t)(b_ * H_ + h) * D_ + d) * T_ + tl] = v;
            }
        }
    }
}

// ---------------------------------------------------------------------------
// proj 2-phase pipelined core with frag-ahead (R15, unchanged).
// ---------------------------------------------------------------------------
#define RD8(CB, KS, FX, FW)                                                      \
    _Pragma("unroll") for (int i_ = 0; i_ < 4; ++i_) {                           \
        FX[i_] = *(const bf16x8*)((CB) + (KS) * 8192  + xoff[i_]);               \
        FW[i_] = *(const bf16x8*)((CB) + (KS) * 16384 + woff[i_]);               \
    }

#define PPH(ISSUE, GATE, FX, FW, ...)                                            \
  {                                                                              \
    ISSUE;                                                                       \
    if ((GATE) == 6)      asm volatile("s_waitcnt vmcnt(6)" ::: "memory");       \
    else if ((GATE) == 3) asm volatile("s_waitcnt vmcnt(3)" ::: "memory");       \
    else if ((GATE) == 0) asm volatile("s_waitcnt vmcnt(0)" ::: "memory");       \
    __builtin_amdgcn_s_barrier();                                                \
    asm volatile("" ::: "memory");                                               \
    __VA_ARGS__;                                                                 \
    __builtin_amdgcn_sched_barrier(0);                                           \
    __builtin_amdgcn_s_setprio(1);                                               \
    _Pragma("unroll") for (int i = 0; i < 4; ++i)                                \
      _Pragma("unroll") for (int j = 0; j < 4; ++j)                              \
        acc[i][j] = __builtin_amdgcn_mfma_f32_16x16x32_bf16(FW[j], FX[i], acc[i][j], 0, 0, 0); \
    __builtin_amdgcn_s_setprio(0);                                               \
    asm volatile("" ::: "memory");                                               \
    __builtin_amdgcn_s_barrier();                                                \
    asm volatile("" ::: "memory");                                               \
  }

__device__ __forceinline__ void gemm8p_core(const u16* __restrict__ Arow,
                                            const u16* __restrict__ Brow,
                                            char* lds, f32x4 (&acc)[4][4])
{
    int tid  = threadIdx.x;
    int lane = tid & 63, w = tid >> 6;
    int quad = lane >> 4, l15 = lane & 15;
    int wm = w >> 2, wn = w & 3;

    int r  = tid >> 2, s4 = tid & 3;
    int kg = ((s4 - (r >> 1)) & 3) * 8;
    const u16* xsrc  = Arow + (size_t)r * C_ + kg;
    const u16* wsrc0 = Brow + (size_t)r * C_ + kg;
    const u16* wsrc1 = Brow + (size_t)(128 + r) * C_ + kg;
    int wu = w << 10;

    int xoff[4], woff[4];
#pragma unroll
    for (int i = 0; i < 4; ++i) {
        int rx = wm * 64 + i * 16 + l15;
        xoff[i] = rx * 64 + (((rx >> 1) + quad) & 3) * 16;
        int rw = wn * 64 + i * 16 + l15;
        woff[i] = 16384 + rw * 64 + (((rw >> 1) + quad) & 3) * 16;
    }

    auto issue_group = [&](int g) {
        int db = (g >> 1) & 1, ks = g & 1;
        int koff = (g >> 1) * 64 + ks * 32;
        char* ldb = lds + db * 49152;
        async16(xsrc  + koff, ldb + ks * 8192 + wu);
        async16(wsrc0 + koff, ldb + 16384 + ks * 16384 + wu);
        async16(wsrc1 + koff, ldb + 16384 + ks * 16384 + 8192 + wu);
    };

    bf16x8 fAx[4], fAw[4], fBx[4], fBw[4];

    issue_group(0); issue_group(1); issue_group(2);
    asm volatile("s_waitcnt vmcnt(6)" ::: "memory");
    __builtin_amdgcn_s_barrier();
    asm volatile("" ::: "memory");
    RD8(lds, 0, fAx, fAw);

    for (int t = 0; t < NT_ - 1; ++t) {
        char* cb  = lds + (t & 1) * 49152;
        char* cbn = lds + ((t + 1) & 1) * 49152;
        PPH({ issue_group(2 * t + 3); }, 6, fAx, fAw, { RD8(cb, 1, fBx, fBw); });
        if (t < NT_ - 2) {
            PPH({ issue_group(2 * t + 4); }, 6, fBx, fBw, { RD8(cbn, 0, fAx, fAw); });
        } else {
            PPH({}, 3, fBx, fBw, { RD8(cbn, 0, fAx, fAw); });
        }
    }
    {
        char* cb = lds + ((NT_ - 1) & 1) * 49152;
        PPH({}, 0, fAx, fAw, { RD8(cb, 1, fBx, fBw); });
        PPH({}, -1, fBx, fBw, {});
    }
}

// ---------------------------------------------------------------------------
// R17 joint-pass flash attention (causal), S^T/O^T, max-free softmax.
// One K/V stream per block: st = 0..31-jj; Q-tile B (qt=31-jj) always
// active, Q-tile A (qt=jj) active while st <= jj.  Compact LDS offsets:
// sr&7 == l15&7, so the sblk term folds into the ds_read immediate.
// ---------------------------------------------------------------------------
__global__ __launch_bounds__(256, 4) void attn_kernel(
    const u16* __restrict__ Qb, const u16* __restrict__ Kb,
    const u16* __restrict__ Vtb, u16* __restrict__ Yb)
{
    __shared__ u16 SMA[16384];       // Ks0|Ks1|Vs0|Vs1 (4x8KB), reused by epilogue
    u16* Ks0 = SMA;
    u16* Ks1 = SMA + 4096;
    u16* Vs0 = SMA + 8192;
    u16* Vs1 = SMA + 12288;

    int id = blockIdx.x;
    int bh = id & 63;
    int jj = id >> 6;                // 0..15
    int qtA = jj, qtB = 31 - jj;     // A <= 15 < B
    const int nstA = qtA + 1;        // tiles where A participates
    const int nstB = qtB + 1;        // total staged tiles (17..32)

    int tid = threadIdx.x, lane = tid & 63, w = tid >> 6;
    int quad = lane >> 4, l15 = lane & 15;
    int b = bh >> 4, h = bh & 15;

    // compact loop-invariant LDS byte offsets (+ sblk*2048 / n*2048 immediates)
    int koffb0 = l15 * 128 + ((quad + l15) & 7) * 16;
    int koffb1 = l15 * 128 + ((4 + quad + l15) & 7) * 16;
    int voffb[4];
#pragma unroll
    for (int sblk = 0; sblk < 4; ++sblk)
        voffb[sblk] = l15 * 128 + ((sblk * 2 + (quad >> 1) + l15) & 7) * 16 + (quad & 1) * 8;

    // staging chunk assignment (512 chunks of 16B per 8KB tile, 2 passes)
    int cA_ = tid, cB_ = tid + 256;
    int sA = cA_ >> 3, sB = cB_ >> 3;
    int offA = (((cA_ & 7) - sA) & 7) * 8;
    int offB = (((cB_ & 7) - sB) & 7) * 8;
    const u16* Kbase = Kb + (size_t)(b * T_) * C_ + h * 64;
    const u16* Vbase = Vtb + (size_t)bh * D_ * T_;
    int ldsb0 = (w * 64) * 16, ldsb1 = (256 + w * 64) * 16;

    const s16x4 ones = { (short)0x3F80, (short)0x3F80, (short)0x3F80, (short)0x3F80 };
    const f32x4 z4 = {0.f, 0.f, 0.f, 0.f};

    // Q frags for both tiles (hoisted once)
    bf16x8 qfA0, qfA1, qfB0, qfB1;
    {
        const u16* qA = Qb + ((size_t)(b * T_ + qtA * 64 + w * 16 + l15)) * C_ + h * 64;
        qfA0 = *(const bf16x8*)(qA + quad * 8);
        qfA1 = *(const bf16x8*)(qA + 32 + quad * 8);
        const u16* qB = Qb + ((size_t)(b * T_ + qtB * 64 + w * 16 + l15)) * C_ + h * 64;
        qfB0 = *(const bf16x8*)(qB + quad * 8);
        qfB1 = *(const bf16x8*)(qB + 32 + quad * 8);
    }

    f32x4 oA[4], oB[4];
    f32x4 lA = z4, lB = z4;
#pragma unroll
    for (int n = 0; n < 4; ++n) { oA[n] = z4; oB[n] = z4; }

    const u16* kgpA = Kbase + (size_t)sA * C_ + offA;
    const u16* kgpB = Kbase + (size_t)sB * C_ + offB;
    const u16* vgpA = Vbase + sA * T_ + offA;
    const u16* vgpB = Vbase + sB * T_ + offB;

    // prologue: stage tile 0 into buffer 0
    async16(kgpA, (char*)Ks0 + ldsb0);
    async16(kgpB, (char*)Ks0 + ldsb1);
    async16(vgpA, (char*)Vs0 + ldsb0);
    async16(vgpB, (char*)Vs0 + ldsb1);
    kgpA += 64 * C_; kgpB += 64 * C_; vgpA += 64; vgpB += 64;

    auto tile_body = [&](int st, const u16* K_, const u16* V_, char* Kpf, char* Vpf) {
        __syncthreads();   // tile st resident (implicit vmcnt drain); prev reads done
        if (st + 1 < nstB) {
            async16(kgpA, Kpf + ldsb0);
            async16(kgpB, Kpf + ldsb1);
            async16(vgpA, Vpf + ldsb0);
            async16(vgpB, Vpf + ldsb1);
        }
        kgpA += 64 * C_; kgpB += 64 * C_; vgpA += 64; vgpB += 64;

        // ================= Q-tile B (always) =================
        {
            f32x4 sv[4];
#pragma unroll
            for (int sblk = 0; sblk < 4; ++sblk) {
                bf16x8 k0 = *(const bf16x8*)((const char*)K_ + sblk * 2048 + koffb0);
                bf16x8 k1 = *(const bf16x8*)((const char*)K_ + sblk * 2048 + koffb1);
                f32x4 t0 = __builtin_amdgcn_mfma_f32_16x16x32_bf16(k0, qfB0, z4, 0, 0, 0);
                sv[sblk] = __builtin_amdgcn_mfma_f32_16x16x32_bf16(k1, qfB1, t0, 0, 0, 0);
            }
            if (st == qtB) {   // diagonal: mask s > t (tile-local)
                int tl = w * 16 + l15;
#pragma unroll
                for (int sblk = 0; sblk < 4; ++sblk)
#pragma unroll
                    for (int r = 0; r < 4; ++r)
                        if (sblk * 16 + quad * 4 + r > tl) sv[sblk][r] = -1e30f;
            }
            s16x4 pfrag[4];
#pragma unroll
            for (int sblk = 0; sblk < 4; ++sblk) {
#pragma unroll
                for (int r = 0; r < 4; ++r)
                    sv[sblk][r] = __builtin_amdgcn_exp2f(sv[sblk][r]);
                uint2 pk;
                pk.x = pk_bf16(sv[sblk][0], sv[sblk][1]);
                pk.y = pk_bf16(sv[sblk][2], sv[sblk][3]);
                pfrag[sblk] = *(s16x4*)&pk;
                lB = __builtin_amdgcn_mfma_f32_16x16x16bf16_1k(ones, pfrag[sblk], lB, 0, 0, 0);
            }
#pragma unroll
            for (int n = 0; n < 4; ++n)
#pragma unroll
                for (int sblk = 0; sblk < 4; ++sblk) {
                    s16x4 va = *(const s16x4*)((const char*)V_ + n * 2048 + voffb[sblk]);
                    oB[n] = __builtin_amdgcn_mfma_f32_16x16x16bf16_1k(va, pfrag[sblk], oB[n], 0, 0, 0);
                }
        }

        // ================= Q-tile A (st <= qtA; block-uniform) =================
        if (st < nstA) {
            f32x4 sv[4];
#pragma unroll
            for (int sblk = 0; sblk < 4; ++sblk) {
                bf16x8 k0 = *(const bf16x8*)((const char*)K_ + sblk * 2048 + koffb0);
                bf16x8 k1 = *(const bf16x8*)((const char*)K_ + sblk * 2048 + koffb1);
                f32x4 t0 = __builtin_amdgcn_mfma_f32_16x16x32_bf16(k0, qfA0, z4, 0, 0, 0);
                sv[sblk] = __builtin_amdgcn_mfma_f32_16x16x32_bf16(k1, qfA1, t0, 0, 0, 0);
            }
            if (st == qtA) {
                int tl = w * 16 + l15;
#pragma unroll
                for (int sblk = 0; sblk < 4; ++sblk)
#pragma unroll
                    for (int r = 0; r < 4; ++r)
                        if (sblk * 16 + quad * 4 + r > tl) sv[sblk][r] = -1e30f;
            }
            s16x4 pfrag[4];
#pragma unroll
            for (int sblk = 0; sblk < 4; ++sblk) {
#pragma unroll
                for (int r = 0; r < 4; ++r)
                    sv[sblk][r] = __builtin_amdgcn_exp2f(sv[sblk][r]);
                uint2 pk;
                pk.x = pk_bf16(sv[sblk][0], sv[sblk][1]);
                pk.y = pk_bf16(sv[sblk][2], sv[sblk][3]);
                pfrag[sblk] = *(s16x4*)&pk;
                lA = __builtin_amdgcn_mfma_f32_16x16x16bf16_1k(ones, pfrag[sblk], lA, 0, 0, 0);
            }
#pragma unroll
            for (int n = 0; n < 4; ++n)
#pragma unroll
                for (int sblk = 0; sblk < 4; ++sblk) {
                    s16x4 va = *(const s16x4*)((const char*)V_ + n * 2048 + voffb[sblk]);
                    oA[n] = __builtin_amdgcn_mfma_f32_16x16x16bf16_1k(va, pfrag[sblk], oA[n], 0, 0, 0);
                }
        }
    };

    for (int st = 0; st < nstB; st += 2) {
        tile_body(st, Ks0, Vs0, (char*)Ks1, (char*)Vs1);
        if (st + 1 < nstB)
            tile_body(st + 1, Ks1, Vs1, (char*)Ks0, (char*)Vs0);
    }

    // epilogue: LDS transpose (wave-private, stride 72), A then B
    __syncthreads();                 // all waves done reading K/V LDS
    u16* PW = SMA + w * 1152;        // 16 rows x 72 elems per wave
    {
        float inv = 1.0f / lA[0];
#pragma unroll
        for (int n = 0; n < 4; ++n) {
            uint2 pk;
            pk.x = pk_bf16(oA[n][0] * inv, oA[n][1] * inv);
            pk.y = pk_bf16(oA[n][2] * inv, oA[n][3] * inv);
            *(u16x4*)&PW[l15 * 72 + n * 16 + quad * 4] = *(u16x4*)&pk;
        }
    }
    asm volatile("s_waitcnt lgkmcnt(0)" ::: "memory");   // wave-private
#pragma unroll
    for (int st = 0; st < 2; ++st) {
        int tr = st * 8 + (lane >> 3);
        int d8 = (lane & 7) * 8;
        u16x8 v = *(u16x8*)&PW[tr * 72 + d8];
        *(u16x8*)&Yb[(size_t)(b * T_ + qtA * 64 + w * 16 + tr) * C_ + h * 64 + d8] = v;
    }
    asm volatile("s_waitcnt lgkmcnt(0)" ::: "memory");   // A-reads retired before rewrite
    {
        float inv = 1.0f / lB[0];
#pragma unroll
        for (int n = 0; n < 4; ++n) {
            uint2 pk;
            pk.x = pk_bf16(oB[n][0] * inv, oB[n][1] * inv);
            pk.y = pk_bf16(oB[n][2] * inv, oB[n][3] * inv);
            *(u16x4*)&PW[l15 * 72 + n * 16 + quad * 4] = *(u16x4*)&pk;
        }
    }
    asm volatile("s_waitcnt lgkmcnt(0)" ::: "memory");
#pragma unroll
    for (int st = 0; st < 2; ++st) {
        int tr = st * 8 + (lane >> 3);
        int d8 = (lane & 7) * 8;
        u16x8 v = *(u16x8*)&PW[tr * 72 + d8];
        *(u16x8*)&Yb[(size_t)(b * T_ + qtB * 64 + w * 16 + tr) * C_ + h * 64 + d8] = v;
    }
}

// ---------------------------------------------------------------------------
// Output projection on the frag-ahead 2-phase core (unchanged).
// Grid 256 = 8 XCD x 32 = exactly one residency round.
// ---------------------------------------------------------------------------
__global__ __launch_bounds__(512, 2) void proj_gemm8(
    const u16* __restrict__ Yb, const u16* __restrict__ Wob,
    const float* __restrict__ bo, float* __restrict__ out)
{
    __shared__ __attribute__((aligned(128))) char LDSRAW[98304];

    int id = blockIdx.x;
    int wg = (id & 7) * 32 + (id >> 3);
    int bm = wg >> 2, bn = wg & 3;
    int m0 = bm * 128, n0 = bn * 256;

    f32x4 acc[4][4];
    const f32x4 z4 = {0.f, 0.f, 0.f, 0.f};
#pragma unroll
    for (int i = 0; i < 4; ++i)
#pragma unroll
        for (int j = 0; j < 4; ++j) acc[i][j] = z4;

    gemm8p_core(Yb + (size_t)m0 * C_, Wob + (size_t)n0 * C_, LDSRAW, acc);

    int tid = threadIdx.x, lane = tid & 63, w = tid >> 6;
    int quad = lane >> 4, l15 = lane & 15;
    int wm = w >> 2, wn = w & 3;

#pragma unroll
    for (int j = 0; j < 4; ++j) {
        int ch = n0 + wn * 64 + j * 16 + quad * 4;
        f32x4 bv = *(const f32x4*)&bo[ch];
#pragma unroll
        for (int i = 0; i < 4; ++i) {
            int t = m0 + wm * 64 + i * 16 + l15;
            f32x4 v = acc[i][j] + bv;
            *(f32x4*)&out[(size_t)t * C_ + ch] = v;
        }
    }
}

// ---------------------------------------------------------------------------
// launch
// ---------------------------------------------------------------------------
extern "C" void kernel_launch(void* const* d_in, const int* in_sizes, int n_in,
                              void* d_out, int out_size, void* d_ws, size_t ws_size,
                              hipStream_t stream) {
    const float* X  = (const float*)d_in[0];
    const float* Wq = (const float*)d_in[1];
    const float* Wk = (const float*)d_in[2];
    const float* Wv = (const float*)d_in[3];
    const float* Wo = (const float*)d_in[4];
    const float* bo = (const float*)d_in[5];

    char* ws = (char*)d_ws;
    u16* Xb  = (u16*)(ws);                       // 16 MB  [BT, C] bf16
    u16* Wqb = (u16*)(ws + (16u << 20));         //  2 MB  } contiguous
    u16* Wkb = (u16*)(ws + (18u << 20));         //  2 MB  } [3072,1024]
    u16* Wvb = (u16*)(ws + (20u << 20));         //  2 MB  } Wcat
    u16* Wob = (u16*)(ws + (22u << 20));         //  2 MB
    u16* Qb  = (u16*)(ws + (24u << 20));         // 16 MB  [BT, C] (pre-scaled)
    u16* Kb  = (u16*)(ws + (40u << 20));         // 16 MB  [BT, C]
    u16* Vtb = (u16*)(ws + (56u << 20));         // 16 MB  [B,H,D,T]
    u16* Yb  = (u16*)(ws + (72u << 20));         // 16 MB  [BT, C]

    cast_all_kernel<<<dim3(8192 + 4 * 1024), 256, 0, stream>>>(
        X, Wq, Wk, Wv, Wo, Xb, Wqb, Wkb, Wvb, Wob);

    qkv_mix512<<<dim3(512), 512, 0, stream>>>(Xb, Wqb, Qb, Kb, Vtb);
    attn_kernel<<<dim3(1024), 256, 0, stream>>>(Qb, Kb, Vtb, Yb);
    proj_gemm8<<<dim3(256), 512, 0, stream>>>(Yb, Wob, bo, (float*)d_out);
}

// Round 7
// 239.675 us; speedup vs baseline: 1.1557x; 1.1557x over previous
//
#include <hip/hip_runtime.h>
#include <hip/hip_bf16.h>
#include <stdint.h>

// ---------------------------------------------------------------------------
// SplitCausalSelfAttention on MI355X (gfx950), bf16 MFMA implementation.
// B=4, T=2048, C=1024, H=16, D=64.
// R18: joint-pass attention, register-budgeted.  R17's spill post-mortem:
//      VGPR cap 128 (launch_bounds 256,4) + 56 persistent regs -> scratch
//      spills (WRITE_SIZE 210MB vs 16MB ideal) -> memory-bound at 103us.
//      Fix: (1) launch_bounds(256,3) -> 168-VGPR cap, 3 blocks/CU (12
//      waves, LDS 32KB fits); (2) shared-operand restructure: K-frags
//      loaded ONCE per sblk feeding both Q-tiles, sv exp'd/packed
//      immediately (transient life 1 iter, peak live ~110), V-frags
//      loaded once feeding both oB/oA.  Halves K/V ds_reads in shared
//      stages on top of the -26% staging.  Same math as R17 (passed).
//      qkv (mix512)/proj/cast unchanged from R16 for attribution.
// ---------------------------------------------------------------------------

typedef unsigned short u16;
typedef __attribute__((ext_vector_type(8))) __bf16 bf16x8;  // 4 VGPRs (A/B frag, K=32)
typedef __attribute__((ext_vector_type(4))) float  f32x4;   // C/D frag
typedef __attribute__((ext_vector_type(4))) unsigned short u16x4;
typedef __attribute__((ext_vector_type(8))) unsigned short u16x8;
typedef __attribute__((ext_vector_type(4))) short s16x4;    // 2 VGPRs (A/B frag, K=16)

#define B_  4
#define T_  2048
#define C_  1024
#define H_  16
#define D_  64
#define BT_ (B_ * T_)
#define NT_ 16        // K-tiles of 64 over K=1024

// scale = 1/sqrt(D) folded with log2(e) so softmax uses exp2
#define Q_SCALE 0.1803368801111204f

__device__ __forceinline__ u16 f32_to_bf16(float f) {
    unsigned int u = __float_as_uint(f);
    unsigned int r = (u + 0x7FFFu + ((u >> 16) & 1u)) >> 16;
    return (u16)r;
}

__device__ __forceinline__ unsigned int pk_bf16(float a, float b) {
    float2 f2; f2.x = a; f2.y = b;
    __hip_bfloat162 h = __float22bfloat162_rn(f2);
    return *(unsigned int*)&h;
}

__device__ __forceinline__ void async16(const void* g, void* lds) {
    __builtin_amdgcn_global_load_lds(
        (const __attribute__((address_space(1))) void*)g,
        (__attribute__((address_space(3))) void*)lds, 16, 0, 0);
}

// ---------------------------------------------------------------------------
// single cast kernel: X (8192 blocks) + 4 weights (1024 blocks each)
// ---------------------------------------------------------------------------
__global__ void cast_all_kernel(const float* __restrict__ X,
                                const float* __restrict__ w0, const float* __restrict__ w1,
                                const float* __restrict__ w2, const float* __restrict__ w3,
                                u16* __restrict__ xo,
                                u16* __restrict__ o0, u16* __restrict__ o1,
                                u16* __restrict__ o2, u16* __restrict__ o3) {
    int id = blockIdx.x;
    const float* in; u16* out; int i;
    if (id < 8192) {
        in = X; out = xo; i = id * 256 + threadIdx.x;
    } else {
        int k = (id - 8192) >> 10;
        in  = (k == 0) ? w0 : (k == 1) ? w1 : (k == 2) ? w2 : w3;
        out = (k == 0) ? o0 : (k == 1) ? o1 : (k == 2) ? o2 : o3;
        i = ((id - 8192) & 1023) * 256 + threadIdx.x;
    }
    float4 v = ((const float4*)in)[i];
    u16x4 o;
    o[0] = f32_to_bf16(v.x); o[1] = f32_to_bf16(v.y);
    o[2] = f32_to_bf16(v.z); o[3] = f32_to_bf16(v.w);
    ((u16x4*)out)[i] = o;
}

// ---------------------------------------------------------------------------
// Full-tile 256x256 4-phase core (R13, non-swap only).
// ---------------------------------------------------------------------------
#define QPHASE(CB, MH, NH, DOISSUE, G, GATE)                                      \
  {                                                                               \
    if ((NH) == 0) {                                                              \
      _Pragma("unroll")                                                           \
      for (int f = 0; f < 4; ++f) {                                               \
        _Pragma("unroll")                                                         \
        for (int ks = 0; ks < 2; ++ks)                                            \
          xf[f][ks] = *(const bf16x8*)((CB) + (MH) * 16384 + axoff[f][ks]);       \
      }                                                                           \
    }                                                                             \
    if ((MH) == 0) {                                                              \
      _Pragma("unroll")                                                           \
      for (int e = 0; e < 2; ++e) {                                               \
        _Pragma("unroll")                                                         \
        for (int ks = 0; ks < 2; ++ks)                                            \
          wf[NH][e][ks] = *(const bf16x8*)((CB) + (NH) * 16384 + bwoff[e][ks]);   \
      }                                                                           \
    }                                                                             \
    if (DOISSUE) issue_unit(G);                                                   \
    if ((GATE) == 4)      asm volatile("s_waitcnt vmcnt(4)" ::: "memory");        \
    else if ((GATE) == 2) asm volatile("s_waitcnt vmcnt(2)" ::: "memory");        \
    else if ((GATE) == 0) asm volatile("s_waitcnt vmcnt(0)" ::: "memory");        \
    __builtin_amdgcn_s_barrier();                                                 \
    asm volatile("" ::: "memory");                                                \
    __builtin_amdgcn_s_setprio(1);                                                \
    _Pragma("unroll")                                                             \
    for (int f = 0; f < 4; ++f) {                                                 \
      _Pragma("unroll")                                                           \
      for (int e = 0; e < 2; ++e) {                                               \
        f32x4 a_ = acc[(MH) * 4 + f][(NH) * 2 + e];                               \
        a_ = __builtin_amdgcn_mfma_f32_16x16x32_bf16(wf[NH][e][0], xf[f][0], a_, 0, 0, 0); \
        a_ = __builtin_amdgcn_mfma_f32_16x16x32_bf16(wf[NH][e][1], xf[f][1], a_, 0, 0, 0); \
        acc[(MH) * 4 + f][(NH) * 2 + e] = a_;                                     \
      }                                                                           \
    }                                                                             \
    __builtin_amdgcn_s_setprio(0);                                                \
    asm volatile("" ::: "memory");                                                \
    __builtin_amdgcn_s_barrier();                                                 \
    asm volatile("" ::: "memory");                                                \
  }

__device__ __forceinline__ void qkv256_core(const u16* __restrict__ Arow,
                                            const u16* __restrict__ Brow,
                                            char* lds, f32x4 (&acc)[8][4])
{
    int tid = threadIdx.x, lane = tid & 63, w = tid >> 6;
    int quad = lane >> 4, l15 = lane & 15;
    int wm = w >> 2, wn = w & 3;

    int gc = (((tid & 7) - (tid >> 3)) & 7) * 8;
    const u16* xsrc0 = Arow + (size_t)(tid >> 3) * C_ + gc;
    const u16* xsrc1 = xsrc0 + (size_t)64 * C_;
    const u16* wsrc0 = Brow + (size_t)(tid >> 3) * C_ + gc;
    const u16* wsrc1 = wsrc0 + (size_t)64 * C_;

    auto issue_unit = [&](int g) {
        int u = g & 3, kt = g >> 2;
        char* d = lds + ((kt & 1) << 16) + (u << 14) + (w << 10);
        size_t off = (size_t)(u & 1) * (128 * C_) + (size_t)kt * 64;
        const u16* s0 = (u < 2) ? xsrc0 : wsrc0;
        const u16* s1 = (u < 2) ? xsrc1 : wsrc1;
        async16(s0 + off, d);
        async16(s1 + off, d + 8192);
    };

    int axoff[4][2], bwoff[2][2];
#pragma unroll
    for (int f = 0; f < 4; ++f) {
        int r = wm * 64 + f * 16 + l15;
#pragma unroll
        for (int ks = 0; ks < 2; ++ks)
            axoff[f][ks] = r * 128 + (((ks * 4 + quad + r) & 7) << 4);
    }
#pragma unroll
    for (int e = 0; e < 2; ++e) {
        int r = wn * 32 + e * 16 + l15;
#pragma unroll
        for (int ks = 0; ks < 2; ++ks)
            bwoff[e][ks] = 32768 + r * 128 + (((ks * 4 + quad + r) & 7) << 4);
    }

    bf16x8 xf[4][2];       // A-frags for current mh (read at nh==0 phases)
    bf16x8 wf[2][2][2];    // B-frags for both nh (read at mh==0 phases)

    issue_unit(0); issue_unit(2); issue_unit(3); issue_unit(1);
    asm volatile("s_waitcnt vmcnt(4)" ::: "memory");
    __builtin_amdgcn_s_barrier();
    asm volatile("" ::: "memory");

    for (int t = 0; t < NT_ - 1; ++t) {
        char* cb = lds + ((t & 1) << 16);
        int g4 = (t + 1) << 2;
        QPHASE(cb, 0, 0, 1, g4 + 0, 4);    // reads u0,u2; issue next.u0
        QPHASE(cb, 0, 1, 1, g4 + 2, 4);    // reads u3;    issue next.u2
        QPHASE(cb, 1, 0, 1, g4 + 3, -1);   // reads u1;    issue next.u3
        QPHASE(cb, 1, 1, 1, g4 + 1, 4);    // pure reg;    issue next.u1
    }
    {   // peeled last tile (15, odd -> dbuf 1): tail drain 2 -> 0
        char* cb = lds + 65536;
        QPHASE(cb, 0, 0, 0, 0, 2);
        QPHASE(cb, 0, 1, 0, 0, 0);
        QPHASE(cb, 1, 0, 0, 0, -1);
        QPHASE(cb, 1, 1, 0, 0, -1);
    }
}

// ---------------------------------------------------------------------------
// Half-tile 128x256 core (V panels, swapped operands).  (R16)
// ---------------------------------------------------------------------------
__device__ __forceinline__ void qkv128v_core(const u16* __restrict__ Arow,
                                             const u16* __restrict__ Brow,
                                             char* lds, f32x4 (&acc)[4][4])
{
    int tid = threadIdx.x, lane = tid & 63, w = tid >> 6;
    int quad = lane >> 4, l15 = lane & 15;
    int wm = w >> 2, wn = w & 3;

    int gc = (((tid & 7) - (tid >> 3)) & 7) * 8;
    const u16* asrc  = Arow + (size_t)(tid >> 3) * C_ + gc;
    const u16* bsrc0 = Brow + (size_t)(tid >> 3) * C_ + gc;
    const u16* bsrc1 = bsrc0 + (size_t)64 * C_;

    auto issue3 = [&](int kt) {
        char* db = lds + ((kt & 1) << 16) + (w << 10);
        int ko = kt * 64;
        async16(asrc + ko,                       db);
        async16(asrc + ko + (size_t)64 * C_,     db + 8192);
        async16(bsrc0 + ko,                      db + 32768);
        async16(bsrc1 + ko,                      db + 32768 + 8192);
        async16(bsrc0 + ko + (size_t)128 * C_,   db + 49152);
        async16(bsrc1 + ko + (size_t)128 * C_,   db + 49152 + 8192);
    };

    int axoff[4][2], bwoff[2][2];
#pragma unroll
    for (int f = 0; f < 4; ++f) {
        int r = wm * 64 + f * 16 + l15;
#pragma unroll
        for (int ks = 0; ks < 2; ++ks)
            axoff[f][ks] = r * 128 + (((ks * 4 + quad + r) & 7) << 4);
    }
#pragma unroll
    for (int e = 0; e < 2; ++e) {
        int r = wn * 32 + e * 16 + l15;
#pragma unroll
        for (int ks = 0; ks < 2; ++ks)
            bwoff[e][ks] = 32768 + r * 128 + (((ks * 4 + quad + r) & 7) << 4);
    }

    bf16x8 xf[4][2], wf[2][2];

    issue3(0);

    for (int t = 0; t < NT_; ++t) {
        char* cb = lds + ((t & 1) << 16);
        if (t + 1 < NT_) issue3(t + 1);
        if (t == NT_ - 1) asm volatile("s_waitcnt vmcnt(0)" ::: "memory");
        else              asm volatile("s_waitcnt vmcnt(6)" ::: "memory");
        __builtin_amdgcn_s_barrier();
        asm volatile("" ::: "memory");

#pragma unroll
        for (int f = 0; f < 4; ++f)
#pragma unroll
            for (int ks = 0; ks < 2; ++ks)
                xf[f][ks] = *(const bf16x8*)(cb + axoff[f][ks]);
#pragma unroll
        for (int e = 0; e < 2; ++e)
#pragma unroll
            for (int ks = 0; ks < 2; ++ks)
                wf[e][ks] = *(const bf16x8*)(cb + bwoff[e][ks]);
        __builtin_amdgcn_s_setprio(1);
#pragma unroll
        for (int f = 0; f < 4; ++f)
#pragma unroll
            for (int e = 0; e < 2; ++e) {
                f32x4 a_ = acc[f][e];
                a_ = __builtin_amdgcn_mfma_f32_16x16x32_bf16(xf[f][0], wf[e][0], a_, 0, 0, 0);
                a_ = __builtin_amdgcn_mfma_f32_16x16x32_bf16(xf[f][1], wf[e][1], a_, 0, 0, 0);
                acc[f][e] = a_;
            }
        __builtin_amdgcn_s_setprio(0);

#pragma unroll
        for (int e = 0; e < 2; ++e)
#pragma unroll
            for (int ks = 0; ks < 2; ++ks)
                wf[e][ks] = *(const bf16x8*)(cb + 16384 + bwoff[e][ks]);
        __builtin_amdgcn_s_setprio(1);
#pragma unroll
        for (int f = 0; f < 4; ++f)
#pragma unroll
            for (int e = 0; e < 2; ++e) {
                f32x4 a_ = acc[f][2 + e];
                a_ = __builtin_amdgcn_mfma_f32_16x16x32_bf16(xf[f][0], wf[e][0], a_, 0, 0, 0);
                a_ = __builtin_amdgcn_mfma_f32_16x16x32_bf16(xf[f][1], wf[e][1], a_, 0, 0, 0);
                acc[f][2 + e] = a_;
            }
        __builtin_amdgcn_s_setprio(0);
        asm volatile("" ::: "memory");
        __builtin_amdgcn_s_barrier();
        asm volatile("" ::: "memory");
    }
}

// ---------------------------------------------------------------------------
// Fused QKV, mixed grid 512 (R16).
// ---------------------------------------------------------------------------
__global__ __launch_bounds__(512, 2) void qkv_mix512(
    const u16* __restrict__ Xb, const u16* __restrict__ Wcat,
    u16* __restrict__ Qb, u16* __restrict__ Kb, u16* __restrict__ Vtb)
{
    __shared__ __attribute__((aligned(128))) char LDSRAW[131072];

    int id = blockIdx.x;
    int tid = threadIdx.x, lane = tid & 63, w = tid >> 6;
    int quad = lane >> 4, l15 = lane & 15;
    int wm = w >> 2, wn = w & 3;

    if (id < 256) {
        int ti = (id & 7) * 32 + (id >> 3);
        int bm = ti & 31, bn = ti >> 5;
        int m0 = bm * 256, chb = bn * 256;

        f32x4 acc[8][4];
        const f32x4 z4 = {0.f, 0.f, 0.f, 0.f};
#pragma unroll
        for (int i = 0; i < 8; ++i)
#pragma unroll
            for (int j = 0; j < 4; ++j) acc[i][j] = z4;

        qkv256_core(Xb + (size_t)m0 * C_, Wcat + (size_t)chb * C_, LDSRAW, acc);

#pragma unroll
        for (int mi = 0; mi < 8; ++mi) {
            size_t trow = (size_t)(m0 + (mi >> 2) * 128 + wm * 64 + (mi & 3) * 16 + l15) * C_;
#pragma unroll
            for (int nj = 0; nj < 4; ++nj) {
                int colb = chb + (nj >> 1) * 128 + wn * 32 + (nj & 1) * 16 + quad * 4;
                u16* OUT = (colb < 1024) ? Qb : Kb;
                float sc = (colb < 1024) ? Q_SCALE : 1.0f;
                u16x4 v;
#pragma unroll
                for (int rr = 0; rr < 4; ++rr) v[rr] = f32_to_bf16(acc[mi][nj][rr] * sc);
                *(u16x4*)&OUT[trow + (colb & 1023)] = v;
            }
        }
    } else {
        int id2 = id - 256;
        int hw = (id2 & 7) * 32 + (id2 >> 3);
        int vt = hw >> 6;
        int bm = (hw & 63) >> 1, half = hw & 1;
        int m0h = bm * 256 + half * 128;
        int chb = 2048 + vt * 256;

        f32x4 acc[4][4];
        const f32x4 z4 = {0.f, 0.f, 0.f, 0.f};
#pragma unroll
        for (int i = 0; i < 4; ++i)
#pragma unroll
            for (int j = 0; j < 4; ++j) acc[i][j] = z4;

        qkv128v_core(Xb + (size_t)m0h * C_, Wcat + (size_t)chb * C_, LDSRAW, acc);

#pragma unroll
        for (int mi = 0; mi < 4; ++mi) {
            int t0 = m0h + wm * 64 + mi * 16 + quad * 4;
            int b_ = t0 >> 11, tl = t0 & (T_ - 1);
#pragma unroll
            for (int nj = 0; nj < 4; ++nj) {
                int ch = chb + (nj >> 1) * 128 + wn * 32 + (nj & 1) * 16 + l15;
                int h = (ch >> 6) & 15, d = ch & 63;
                u16x4 v;
#pragma unroll
                for (int rr = 0; rr < 4; ++rr) v[rr] = f32_to_bf16(acc[mi][nj][rr]);
                *(u16x4*)&Vtb[((size_t)(b_ * H_ + h) * D_ + d) * T_ + tl] = v;
            }
        }
    }
}

// ---------------------------------------------------------------------------
// proj 2-phase pipelined core with frag-ahead (R15, unchanged).
// ---------------------------------------------------------------------------
#define RD8(CB, KS, FX, FW)                                                      \
    _Pragma("unroll") for (int i_ = 0; i_ < 4; ++i_) {                           \
        FX[i_] = *(const bf16x8*)((CB) + (KS) * 8192  + xoff[i_]);               \
        FW[i_] = *(const bf16x8*)((CB) + (KS) * 16384 + woff[i_]);               \
    }

#define PPH(ISSUE, GATE, FX, FW, ...)                                            \
  {                                                                              \
    ISSUE;                                                                       \
    if ((GATE) == 6)      asm volatile("s_waitcnt vmcnt(6)" ::: "memory");       \
    else if ((GATE) == 3) asm volatile("s_waitcnt vmcnt(3)" ::: "memory");       \
    else if ((GATE) == 0) asm volatile("s_waitcnt vmcnt(0)" ::: "memory");       \
    __builtin_amdgcn_s_barrier();                                                \
    asm volatile("" ::: "memory");                                               \
    __VA_ARGS__;                                                                 \
    __builtin_amdgcn_sched_barrier(0);                                           \
    __builtin_amdgcn_s_setprio(1);                                               \
    _Pragma("unroll") for (int i = 0; i < 4; ++i)                                \
      _Pragma("unroll") for (int j = 0; j < 4; ++j)                              \
        acc[i][j] = __builtin_amdgcn_mfma_f32_16x16x32_bf16(FW[j], FX[i], acc[i][j], 0, 0, 0); \
    __builtin_amdgcn_s_setprio(0);                                               \
    asm volatile("" ::: "memory");                                               \
    __builtin_amdgcn_s_barrier();                                                \
    asm volatile("" ::: "memory");                                               \
  }

__device__ __forceinline__ void gemm8p_core(const u16* __restrict__ Arow,
                                            const u16* __restrict__ Brow,
                                            char* lds, f32x4 (&acc)[4][4])
{
    int tid  = threadIdx.x;
    int lane = tid & 63, w = tid >> 6;
    int quad = lane >> 4, l15 = lane & 15;
    int wm = w >> 2, wn = w & 3;

    int r  = tid >> 2, s4 = tid & 3;
    int kg = ((s4 - (r >> 1)) & 3) * 8;
    const u16* xsrc  = Arow + (size_t)r * C_ + kg;
    const u16* wsrc0 = Brow + (size_t)r * C_ + kg;
    const u16* wsrc1 = Brow + (size_t)(128 + r) * C_ + kg;
    int wu = w << 10;

    int xoff[4], woff[4];
#pragma unroll
    for (int i = 0; i < 4; ++i) {
        int rx = wm * 64 + i * 16 + l15;
        xoff[i] = rx * 64 + (((rx >> 1) + quad) & 3) * 16;
        int rw = wn * 64 + i * 16 + l15;
        woff[i] = 16384 + rw * 64 + (((rw >> 1) + quad) & 3) * 16;
    }

    auto issue_group = [&](int g) {
        int db = (g >> 1) & 1, ks = g & 1;
        int koff = (g >> 1) * 64 + ks * 32;
        char* ldb = lds + db * 49152;
        async16(xsrc  + koff, ldb + ks * 8192 + wu);
        async16(wsrc0 + koff, ldb + 16384 + ks * 16384 + wu);
        async16(wsrc1 + koff, ldb + 16384 + ks * 16384 + 8192 + wu);
    };

    bf16x8 fAx[4], fAw[4], fBx[4], fBw[4];

    issue_group(0); issue_group(1); issue_group(2);
    asm volatile("s_waitcnt vmcnt(6)" ::: "memory");
    __builtin_amdgcn_s_barrier();
    asm volatile("" ::: "memory");
    RD8(lds, 0, fAx, fAw);

    for (int t = 0; t < NT_ - 1; ++t) {
        char* cb  = lds + (t & 1) * 49152;
        char* cbn = lds + ((t + 1) & 1) * 49152;
        PPH({ issue_group(2 * t + 3); }, 6, fAx, fAw, { RD8(cb, 1, fBx, fBw); });
        if (t < NT_ - 2) {
            PPH({ issue_group(2 * t + 4); }, 6, fBx, fBw, { RD8(cbn, 0, fAx, fAw); });
        } else {
            PPH({}, 3, fBx, fBw, { RD8(cbn, 0, fAx, fAw); });
        }
    }
    {
        char* cb = lds + ((NT_ - 1) & 1) * 49152;
        PPH({}, 0, fAx, fAw, { RD8(cb, 1, fBx, fBw); });
        PPH({}, -1, fBx, fBw, {});
    }
}

// ---------------------------------------------------------------------------
// R18 joint-pass flash attention, register-budgeted (see header).
// One K/V stream per block: st = 0..31-jj; Q-tile B (qt=31-jj) always
// active, Q-tile A (qt=jj) active while st <= jj (block-uniform).
// K-frags and V-frags loaded once, shared by both Q-tiles; sv exp'd and
// packed immediately per sblk so transient pressure is 1 iteration.
// ---------------------------------------------------------------------------
__global__ __launch_bounds__(256, 3) void attn_kernel(
    const u16* __restrict__ Qb, const u16* __restrict__ Kb,
    const u16* __restrict__ Vtb, u16* __restrict__ Yb)
{
    __shared__ u16 SMA[16384];       // Ks0|Ks1|Vs0|Vs1 (4x8KB), reused by epilogue
    u16* Ks0 = SMA;
    u16* Ks1 = SMA + 4096;
    u16* Vs0 = SMA + 8192;
    u16* Vs1 = SMA + 12288;

    int id = blockIdx.x;
    int bh = id & 63;
    int jj = id >> 6;                // 0..15
    int qtA = jj, qtB = 31 - jj;     // A <= 15 < B
    const int nstA = qtA + 1;        // tiles where A participates
    const int nstB = qtB + 1;        // total staged tiles (17..32)

    int tid = threadIdx.x, lane = tid & 63, w = tid >> 6;
    int quad = lane >> 4, l15 = lane & 15;
    int b = bh >> 4, h = bh & 15;

    // compact loop-invariant LDS byte offsets (+ sblk*2048 / n*2048 immediates)
    int koffb0 = l15 * 128 + ((quad + l15) & 7) * 16;
    int koffb1 = l15 * 128 + ((4 + quad + l15) & 7) * 16;
    int voffb[4];
#pragma unroll
    for (int sblk = 0; sblk < 4; ++sblk)
        voffb[sblk] = l15 * 128 + ((sblk * 2 + (quad >> 1) + l15) & 7) * 16 + (quad & 1) * 8;

    // staging chunk assignment (512 chunks of 16B per 8KB tile, 2 passes)
    int cA_ = tid, cB_ = tid + 256;
    int sA = cA_ >> 3, sB = cB_ >> 3;
    int offA = (((cA_ & 7) - sA) & 7) * 8;
    int offB = (((cB_ & 7) - sB) & 7) * 8;
    const u16* Kbase = Kb + (size_t)(b * T_) * C_ + h * 64;
    const u16* Vbase = Vtb + (size_t)bh * D_ * T_;
    int ldsb0 = (w * 64) * 16, ldsb1 = (256 + w * 64) * 16;

    const s16x4 ones = { (short)0x3F80, (short)0x3F80, (short)0x3F80, (short)0x3F80 };
    const f32x4 z4 = {0.f, 0.f, 0.f, 0.f};

    // Q frags for both tiles (hoisted once)
    bf16x8 qfA0, qfA1, qfB0, qfB1;
    {
        const u16* qA = Qb + ((size_t)(b * T_ + qtA * 64 + w * 16 + l15)) * C_ + h * 64;
        qfA0 = *(const bf16x8*)(qA + quad * 8);
        qfA1 = *(const bf16x8*)(qA + 32 + quad * 8);
        const u16* qB = Qb + ((size_t)(b * T_ + qtB * 64 + w * 16 + l15)) * C_ + h * 64;
        qfB0 = *(const bf16x8*)(qB + quad * 8);
        qfB1 = *(const bf16x8*)(qB + 32 + quad * 8);
    }

    f32x4 oA[4], oB[4];
    f32x4 lA = z4, lB = z4;
#pragma unroll
    for (int n = 0; n < 4; ++n) { oA[n] = z4; oB[n] = z4; }

    const u16* kgpA = Kbase + (size_t)sA * C_ + offA;
    const u16* kgpB = Kbase + (size_t)sB * C_ + offB;
    const u16* vgpA = Vbase + sA * T_ + offA;
    const u16* vgpB = Vbase + sB * T_ + offB;

    // prologue: stage tile 0 into buffer 0
    async16(kgpA, (char*)Ks0 + ldsb0);
    async16(kgpB, (char*)Ks0 + ldsb1);
    async16(vgpA, (char*)Vs0 + ldsb0);
    async16(vgpB, (char*)Vs0 + ldsb1);
    kgpA += 64 * C_; kgpB += 64 * C_; vgpA += 64; vgpB += 64;

    auto tile_body = [&](int st, const u16* K_, const u16* V_, char* Kpf, char* Vpf) {
        __syncthreads();   // tile st resident (implicit vmcnt drain); prev reads done
        if (st + 1 < nstB) {
            async16(kgpA, Kpf + ldsb0);
            async16(kgpB, Kpf + ldsb1);
            async16(vgpA, Vpf + ldsb0);
            async16(vgpB, Vpf + ldsb1);
        }
        kgpA += 64 * C_; kgpB += 64 * C_; vgpA += 64; vgpB += 64;

        const bool doA = (st < nstA);          // block-uniform
        const int tl = w * 16 + l15;
        s16x4 pfB[4], pfA[4];

        // QK^T, shared K-frags; exp+pack immediately (1-iter transient life)
#pragma unroll
        for (int sblk = 0; sblk < 4; ++sblk) {
            bf16x8 k0 = *(const bf16x8*)((const char*)K_ + sblk * 2048 + koffb0);
            bf16x8 k1 = *(const bf16x8*)((const char*)K_ + sblk * 2048 + koffb1);
            f32x4 svB = __builtin_amdgcn_mfma_f32_16x16x32_bf16(k0, qfB0, z4, 0, 0, 0);
            svB = __builtin_amdgcn_mfma_f32_16x16x32_bf16(k1, qfB1, svB, 0, 0, 0);
            f32x4 svA = z4;
            if (doA) {
                svA = __builtin_amdgcn_mfma_f32_16x16x32_bf16(k0, qfA0, z4, 0, 0, 0);
                svA = __builtin_amdgcn_mfma_f32_16x16x32_bf16(k1, qfA1, svA, 0, 0, 0);
            }
            if (st == qtB) {
#pragma unroll
                for (int r = 0; r < 4; ++r)
                    if (sblk * 16 + quad * 4 + r > tl) svB[r] = -1e30f;
            }
#pragma unroll
            for (int r = 0; r < 4; ++r) svB[r] = __builtin_amdgcn_exp2f(svB[r]);
            uint2 pkB;
            pkB.x = pk_bf16(svB[0], svB[1]);
            pkB.y = pk_bf16(svB[2], svB[3]);
            pfB[sblk] = *(s16x4*)&pkB;
            lB = __builtin_amdgcn_mfma_f32_16x16x16bf16_1k(ones, pfB[sblk], lB, 0, 0, 0);
            if (doA) {
                if (st == qtA) {
#pragma unroll
                    for (int r = 0; r < 4; ++r)
                        if (sblk * 16 + quad * 4 + r > tl) svA[r] = -1e30f;
                }
#pragma unroll
                for (int r = 0; r < 4; ++r) svA[r] = __builtin_amdgcn_exp2f(svA[r]);
                uint2 pkA;
                pkA.x = pk_bf16(svA[0], svA[1]);
                pkA.y = pk_bf16(svA[2], svA[3]);
                pfA[sblk] = *(s16x4*)&pkA;
                lA = __builtin_amdgcn_mfma_f32_16x16x16bf16_1k(ones, pfA[sblk], lA, 0, 0, 0);
            }
        }

        // PV, shared V-frags
#pragma unroll
        for (int n = 0; n < 4; ++n)
#pragma unroll
            for (int sblk = 0; sblk < 4; ++sblk) {
                s16x4 va = *(const s16x4*)((const char*)V_ + n * 2048 + voffb[sblk]);
                oB[n] = __builtin_amdgcn_mfma_f32_16x16x16bf16_1k(va, pfB[sblk], oB[n], 0, 0, 0);
                if (doA)
                    oA[n] = __builtin_amdgcn_mfma_f32_16x16x16bf16_1k(va, pfA[sblk], oA[n], 0, 0, 0);
            }
    };

    for (int st = 0; st < nstB; st += 2) {
        tile_body(st, Ks0, Vs0, (char*)Ks1, (char*)Vs1);
        if (st + 1 < nstB)
            tile_body(st + 1, Ks1, Vs1, (char*)Ks0, (char*)Vs0);
    }

    // epilogue: LDS transpose (wave-private, stride 72), A then B
    __syncthreads();                 // all waves done reading K/V LDS
    u16* PW = SMA + w * 1152;        // 16 rows x 72 elems per wave
    {
        float inv = 1.0f / lA[0];
#pragma unroll
        for (int n = 0; n < 4; ++n) {
            uint2 pk;
            pk.x = pk_bf16(oA[n][0] * inv, oA[n][1] * inv);
            pk.y = pk_bf16(oA[n][2] * inv, oA[n][3] * inv);
            *(u16x4*)&PW[l15 * 72 + n * 16 + quad * 4] = *(u16x4*)&pk;
        }
    }
    asm volatile("s_waitcnt lgkmcnt(0)" ::: "memory");   // wave-private
#pragma unroll
    for (int st = 0; st < 2; ++st) {
        int tr = st * 8 + (lane >> 3);
        int d8 = (lane & 7) * 8;
        u16x8 v = *(u16x8*)&PW[tr * 72 + d8];
        *(u16x8*)&Yb[(size_t)(b * T_ + qtA * 64 + w * 16 + tr) * C_ + h * 64 + d8] = v;
    }
    asm volatile("s_waitcnt lgkmcnt(0)" ::: "memory");   // A-reads retired before rewrite
    {
        float inv = 1.0f / lB[0];
#pragma unroll
        for (int n = 0; n < 4; ++n) {
            uint2 pk;
            pk.x = pk_bf16(oB[n][0] * inv, oB[n][1] * inv);
            pk.y = pk_bf16(oB[n][2] * inv, oB[n][3] * inv);
            *(u16x4*)&PW[l15 * 72 + n * 16 + quad * 4] = *(u16x4*)&pk;
        }
    }
    asm volatile("s_waitcnt lgkmcnt(0)" ::: "memory");
#pragma unroll
    for (int st = 0; st < 2; ++st) {
        int tr = st * 8 + (lane >> 3);
        int d8 = (lane & 7) * 8;
        u16x8 v = *(u16x8*)&PW[tr * 72 + d8];
        *(u16x8*)&Yb[(size_t)(b * T_ + qtB * 64 + w * 16 + tr) * C_ + h * 64 + d8] = v;
    }
}

// ---------------------------------------------------------------------------
// Output projection on the frag-ahead 2-phase core (unchanged).
// Grid 256 = 8 XCD x 32 = exactly one residency round.
// ---------------------------------------------------------------------------
__global__ __launch_bounds__(512, 2) void proj_gemm8(
    const u16* __restrict__ Yb, const u16* __restrict__ Wob,
    const float* __restrict__ bo, float* __restrict__ out)
{
    __shared__ __attribute__((aligned(128))) char LDSRAW[98304];

    int id = blockIdx.x;
    int wg = (id & 7) * 32 + (id >> 3);
    int bm = wg >> 2, bn = wg & 3;
    int m0 = bm * 128, n0 = bn * 256;

    f32x4 acc[4][4];
    const f32x4 z4 = {0.f, 0.f, 0.f, 0.f};
#pragma unroll
    for (int i = 0; i < 4; ++i)
#pragma unroll
        for (int j = 0; j < 4; ++j) acc[i][j] = z4;

    gemm8p_core(Yb + (size_t)m0 * C_, Wob + (size_t)n0 * C_, LDSRAW, acc);

    int tid = threadIdx.x, lane = tid & 63, w = tid >> 6;
    int quad = lane >> 4, l15 = lane & 15;
    int wm = w >> 2, wn = w & 3;

#pragma unroll
    for (int j = 0; j < 4; ++j) {
        int ch = n0 + wn * 64 + j * 16 + quad * 4;
        f32x4 bv = *(const f32x4*)&bo[ch];
#pragma unroll
        for (int i = 0; i < 4; ++i) {
            int t = m0 + wm * 64 + i * 16 + l15;
            f32x4 v = acc[i][j] + bv;
            *(f32x4*)&out[(size_t)t * C_ + ch] = v;
        }
    }
}

// ---------------------------------------------------------------------------
// launch
// ---------------------------------------------------------------------------
extern "C" void kernel_launch(void* const* d_in, const int* in_sizes, int n_in,
                              void* d_out, int out_size, void* d_ws, size_t ws_size,
                              hipStream_t stream) {
    const float* X  = (const float*)d_in[0];
    const float* Wq = (const float*)d_in[1];
    const float* Wk = (const float*)d_in[2];
    const float* Wv = (const float*)d_in[3];
    const float* Wo = (const float*)d_in[4];
    const float* bo = (const float*)d_in[5];

    char* ws = (char*)d_ws;
    u16* Xb  = (u16*)(ws);                       // 16 MB  [BT, C] bf16
    u16* Wqb = (u16*)(ws + (16u << 20));         //  2 MB  } contiguous
    u16* Wkb = (u16*)(ws + (18u << 20));         //  2 MB  } [3072,1024]
    u16* Wvb = (u16*)(ws + (20u << 20));         //  2 MB  } Wcat
    u16* Wob = (u16*)(ws + (22u << 20));         //  2 MB
    u16* Qb  = (u16*)(ws + (24u << 20));         // 16 MB  [BT, C] (pre-scaled)
    u16* Kb  = (u16*)(ws + (40u << 20));         // 16 MB  [BT, C]
    u16* Vtb = (u16*)(ws + (56u << 20));         // 16 MB  [B,H,D,T]
    u16* Yb  = (u16*)(ws + (72u << 20));         // 16 MB  [BT, C]

    cast_all_kernel<<<dim3(8192 + 4 * 1024), 256, 0, stream>>>(
        X, Wq, Wk, Wv, Wo, Xb, Wqb, Wkb, Wvb, Wob);

    qkv_mix512<<<dim3(512), 512, 0, stream>>>(Xb, Wqb, Qb, Kb, Vtb);
    attn_kernel<<<dim3(1024), 256, 0, stream>>>(Qb, Kb, Vtb, Yb);
    proj_gemm8<<<dim3(256), 512, 0, stream>>>(Yb, Wob, bo, (float*)d_out);
}

// Round 8
// 233.664 us; speedup vs baseline: 1.1854x; 1.0257x over previous
//
#include <hip/hip_runtime.h>
#include <hip/hip_bf16.h>
#include <stdint.h>

// ---------------------------------------------------------------------------
// SplitCausalSelfAttention on MI355X (gfx950), bf16 MFMA implementation.
// B=4, T=2048, C=1024, H=16, D=64.
// R19: attn reverted to the R16 two-pass structure (joint-pass R17/R18 was
//      net-negative: register pressure + occupancy 16->12 waves/CU outweighed
//      the -26% staging, which was mostly L2-hit anyway since same-bh blocks
//      share an XCD).  Added T5 s_setprio(1/0) around attn's QK^T and PV
//      MFMA clusters (catalog m191: +4-7% on multi-block-per-CU attn).
//      qkv (mix512) / proj (frag-ahead 2-phase) / cast unchanged from R18.
// ---------------------------------------------------------------------------

typedef unsigned short u16;
typedef __attribute__((ext_vector_type(8))) __bf16 bf16x8;  // 4 VGPRs (A/B frag, K=32)
typedef __attribute__((ext_vector_type(4))) float  f32x4;   // C/D frag
typedef __attribute__((ext_vector_type(4))) unsigned short u16x4;
typedef __attribute__((ext_vector_type(8))) unsigned short u16x8;
typedef __attribute__((ext_vector_type(4))) short s16x4;    // 2 VGPRs (A/B frag, K=16)

#define B_  4
#define T_  2048
#define C_  1024
#define H_  16
#define D_  64
#define BT_ (B_ * T_)
#define NT_ 16        // K-tiles of 64 over K=1024

// scale = 1/sqrt(D) folded with log2(e) so softmax uses exp2
#define Q_SCALE 0.1803368801111204f

__device__ __forceinline__ u16 f32_to_bf16(float f) {
    unsigned int u = __float_as_uint(f);
    unsigned int r = (u + 0x7FFFu + ((u >> 16) & 1u)) >> 16;
    return (u16)r;
}

__device__ __forceinline__ unsigned int pk_bf16(float a, float b) {
    float2 f2; f2.x = a; f2.y = b;
    __hip_bfloat162 h = __float22bfloat162_rn(f2);
    return *(unsigned int*)&h;
}

__device__ __forceinline__ void async16(const void* g, void* lds) {
    __builtin_amdgcn_global_load_lds(
        (const __attribute__((address_space(1))) void*)g,
        (__attribute__((address_space(3))) void*)lds, 16, 0, 0);
}

// ---------------------------------------------------------------------------
// single cast kernel: X (8192 blocks) + 4 weights (1024 blocks each)
// ---------------------------------------------------------------------------
__global__ void cast_all_kernel(const float* __restrict__ X,
                                const float* __restrict__ w0, const float* __restrict__ w1,
                                const float* __restrict__ w2, const float* __restrict__ w3,
                                u16* __restrict__ xo,
                                u16* __restrict__ o0, u16* __restrict__ o1,
                                u16* __restrict__ o2, u16* __restrict__ o3) {
    int id = blockIdx.x;
    const float* in; u16* out; int i;
    if (id < 8192) {
        in = X; out = xo; i = id * 256 + threadIdx.x;
    } else {
        int k = (id - 8192) >> 10;
        in  = (k == 0) ? w0 : (k == 1) ? w1 : (k == 2) ? w2 : w3;
        out = (k == 0) ? o0 : (k == 1) ? o1 : (k == 2) ? o2 : o3;
        i = ((id - 8192) & 1023) * 256 + threadIdx.x;
    }
    float4 v = ((const float4*)in)[i];
    u16x4 o;
    o[0] = f32_to_bf16(v.x); o[1] = f32_to_bf16(v.y);
    o[2] = f32_to_bf16(v.z); o[3] = f32_to_bf16(v.w);
    ((u16x4*)out)[i] = o;
}

// ---------------------------------------------------------------------------
// Full-tile 256x256 4-phase core (R13, non-swap only).
// ---------------------------------------------------------------------------
#define QPHASE(CB, MH, NH, DOISSUE, G, GATE)                                      \
  {                                                                               \
    if ((NH) == 0) {                                                              \
      _Pragma("unroll")                                                           \
      for (int f = 0; f < 4; ++f) {                                               \
        _Pragma("unroll")                                                         \
        for (int ks = 0; ks < 2; ++ks)                                            \
          xf[f][ks] = *(const bf16x8*)((CB) + (MH) * 16384 + axoff[f][ks]);       \
      }                                                                           \
    }                                                                             \
    if ((MH) == 0) {                                                              \
      _Pragma("unroll")                                                           \
      for (int e = 0; e < 2; ++e) {                                               \
        _Pragma("unroll")                                                         \
        for (int ks = 0; ks < 2; ++ks)                                            \
          wf[NH][e][ks] = *(const bf16x8*)((CB) + (NH) * 16384 + bwoff[e][ks]);   \
      }                                                                           \
    }                                                                             \
    if (DOISSUE) issue_unit(G);                                                   \
    if ((GATE) == 4)      asm volatile("s_waitcnt vmcnt(4)" ::: "memory");        \
    else if ((GATE) == 2) asm volatile("s_waitcnt vmcnt(2)" ::: "memory");        \
    else if ((GATE) == 0) asm volatile("s_waitcnt vmcnt(0)" ::: "memory");        \
    __builtin_amdgcn_s_barrier();                                                 \
    asm volatile("" ::: "memory");                                                \
    __builtin_amdgcn_s_setprio(1);                                                \
    _Pragma("unroll")                                                             \
    for (int f = 0; f < 4; ++f) {                                                 \
      _Pragma("unroll")                                                           \
      for (int e = 0; e < 2; ++e) {                                               \
        f32x4 a_ = acc[(MH) * 4 + f][(NH) * 2 + e];                               \
        a_ = __builtin_amdgcn_mfma_f32_16x16x32_bf16(wf[NH][e][0], xf[f][0], a_, 0, 0, 0); \
        a_ = __builtin_amdgcn_mfma_f32_16x16x32_bf16(wf[NH][e][1], xf[f][1], a_, 0, 0, 0); \
        acc[(MH) * 4 + f][(NH) * 2 + e] = a_;                                     \
      }                                                                           \
    }                                                                             \
    __builtin_amdgcn_s_setprio(0);                                                \
    asm volatile("" ::: "memory");                                                \
    __builtin_amdgcn_s_barrier();                                                 \
    asm volatile("" ::: "memory");                                                \
  }

__device__ __forceinline__ void qkv256_core(const u16* __restrict__ Arow,
                                            const u16* __restrict__ Brow,
                                            char* lds, f32x4 (&acc)[8][4])
{
    int tid = threadIdx.x, lane = tid & 63, w = tid >> 6;
    int quad = lane >> 4, l15 = lane & 15;
    int wm = w >> 2, wn = w & 3;

    int gc = (((tid & 7) - (tid >> 3)) & 7) * 8;
    const u16* xsrc0 = Arow + (size_t)(tid >> 3) * C_ + gc;
    const u16* xsrc1 = xsrc0 + (size_t)64 * C_;
    const u16* wsrc0 = Brow + (size_t)(tid >> 3) * C_ + gc;
    const u16* wsrc1 = wsrc0 + (size_t)64 * C_;

    auto issue_unit = [&](int g) {
        int u = g & 3, kt = g >> 2;
        char* d = lds + ((kt & 1) << 16) + (u << 14) + (w << 10);
        size_t off = (size_t)(u & 1) * (128 * C_) + (size_t)kt * 64;
        const u16* s0 = (u < 2) ? xsrc0 : wsrc0;
        const u16* s1 = (u < 2) ? xsrc1 : wsrc1;
        async16(s0 + off, d);
        async16(s1 + off, d + 8192);
    };

    int axoff[4][2], bwoff[2][2];
#pragma unroll
    for (int f = 0; f < 4; ++f) {
        int r = wm * 64 + f * 16 + l15;
#pragma unroll
        for (int ks = 0; ks < 2; ++ks)
            axoff[f][ks] = r * 128 + (((ks * 4 + quad + r) & 7) << 4);
    }
#pragma unroll
    for (int e = 0; e < 2; ++e) {
        int r = wn * 32 + e * 16 + l15;
#pragma unroll
        for (int ks = 0; ks < 2; ++ks)
            bwoff[e][ks] = 32768 + r * 128 + (((ks * 4 + quad + r) & 7) << 4);
    }

    bf16x8 xf[4][2];       // A-frags for current mh (read at nh==0 phases)
    bf16x8 wf[2][2][2];    // B-frags for both nh (read at mh==0 phases)

    issue_unit(0); issue_unit(2); issue_unit(3); issue_unit(1);
    asm volatile("s_waitcnt vmcnt(4)" ::: "memory");
    __builtin_amdgcn_s_barrier();
    asm volatile("" ::: "memory");

    for (int t = 0; t < NT_ - 1; ++t) {
        char* cb = lds + ((t & 1) << 16);
        int g4 = (t + 1) << 2;
        QPHASE(cb, 0, 0, 1, g4 + 0, 4);    // reads u0,u2; issue next.u0
        QPHASE(cb, 0, 1, 1, g4 + 2, 4);    // reads u3;    issue next.u2
        QPHASE(cb, 1, 0, 1, g4 + 3, -1);   // reads u1;    issue next.u3
        QPHASE(cb, 1, 1, 1, g4 + 1, 4);    // pure reg;    issue next.u1
    }
    {   // peeled last tile (15, odd -> dbuf 1): tail drain 2 -> 0
        char* cb = lds + 65536;
        QPHASE(cb, 0, 0, 0, 0, 2);
        QPHASE(cb, 0, 1, 0, 0, 0);
        QPHASE(cb, 1, 0, 0, 0, -1);
        QPHASE(cb, 1, 1, 0, 0, -1);
    }
}

// ---------------------------------------------------------------------------
// Half-tile 128x256 core (V panels, swapped operands).  (R16)
// ---------------------------------------------------------------------------
__device__ __forceinline__ void qkv128v_core(const u16* __restrict__ Arow,
                                             const u16* __restrict__ Brow,
                                             char* lds, f32x4 (&acc)[4][4])
{
    int tid = threadIdx.x, lane = tid & 63, w = tid >> 6;
    int quad = lane >> 4, l15 = lane & 15;
    int wm = w >> 2, wn = w & 3;

    int gc = (((tid & 7) - (tid >> 3)) & 7) * 8;
    const u16* asrc  = Arow + (size_t)(tid >> 3) * C_ + gc;
    const u16* bsrc0 = Brow + (size_t)(tid >> 3) * C_ + gc;
    const u16* bsrc1 = bsrc0 + (size_t)64 * C_;

    auto issue3 = [&](int kt) {
        char* db = lds + ((kt & 1) << 16) + (w << 10);
        int ko = kt * 64;
        async16(asrc + ko,                       db);
        async16(asrc + ko + (size_t)64 * C_,     db + 8192);
        async16(bsrc0 + ko,                      db + 32768);
        async16(bsrc1 + ko,                      db + 32768 + 8192);
        async16(bsrc0 + ko + (size_t)128 * C_,   db + 49152);
        async16(bsrc1 + ko + (size_t)128 * C_,   db + 49152 + 8192);
    };

    int axoff[4][2], bwoff[2][2];
#pragma unroll
    for (int f = 0; f < 4; ++f) {
        int r = wm * 64 + f * 16 + l15;
#pragma unroll
        for (int ks = 0; ks < 2; ++ks)
            axoff[f][ks] = r * 128 + (((ks * 4 + quad + r) & 7) << 4);
    }
#pragma unroll
    for (int e = 0; e < 2; ++e) {
        int r = wn * 32 + e * 16 + l15;
#pragma unroll
        for (int ks = 0; ks < 2; ++ks)
            bwoff[e][ks] = 32768 + r * 128 + (((ks * 4 + quad + r) & 7) << 4);
    }

    bf16x8 xf[4][2], wf[2][2];

    issue3(0);

    for (int t = 0; t < NT_; ++t) {
        char* cb = lds + ((t & 1) << 16);
        if (t + 1 < NT_) issue3(t + 1);
        if (t == NT_ - 1) asm volatile("s_waitcnt vmcnt(0)" ::: "memory");
        else              asm volatile("s_waitcnt vmcnt(6)" ::: "memory");
        __builtin_amdgcn_s_barrier();
        asm volatile("" ::: "memory");

#pragma unroll
        for (int f = 0; f < 4; ++f)
#pragma unroll
            for (int ks = 0; ks < 2; ++ks)
                xf[f][ks] = *(const bf16x8*)(cb + axoff[f][ks]);
#pragma unroll
        for (int e = 0; e < 2; ++e)
#pragma unroll
            for (int ks = 0; ks < 2; ++ks)
                wf[e][ks] = *(const bf16x8*)(cb + bwoff[e][ks]);
        __builtin_amdgcn_s_setprio(1);
#pragma unroll
        for (int f = 0; f < 4; ++f)
#pragma unroll
            for (int e = 0; e < 2; ++e) {
                f32x4 a_ = acc[f][e];
                a_ = __builtin_amdgcn_mfma_f32_16x16x32_bf16(xf[f][0], wf[e][0], a_, 0, 0, 0);
                a_ = __builtin_amdgcn_mfma_f32_16x16x32_bf16(xf[f][1], wf[e][1], a_, 0, 0, 0);
                acc[f][e] = a_;
            }
        __builtin_amdgcn_s_setprio(0);

#pragma unroll
        for (int e = 0; e < 2; ++e)
#pragma unroll
            for (int ks = 0; ks < 2; ++ks)
                wf[e][ks] = *(const bf16x8*)(cb + 16384 + bwoff[e][ks]);
        __builtin_amdgcn_s_setprio(1);
#pragma unroll
        for (int f = 0; f < 4; ++f)
#pragma unroll
            for (int e = 0; e < 2; ++e) {
                f32x4 a_ = acc[f][2 + e];
                a_ = __builtin_amdgcn_mfma_f32_16x16x32_bf16(xf[f][0], wf[e][0], a_, 0, 0, 0);
                a_ = __builtin_amdgcn_mfma_f32_16x16x32_bf16(xf[f][1], wf[e][1], a_, 0, 0, 0);
                acc[f][2 + e] = a_;
            }
        __builtin_amdgcn_s_setprio(0);
        asm volatile("" ::: "memory");
        __builtin_amdgcn_s_barrier();
        asm volatile("" ::: "memory");
    }
}

// ---------------------------------------------------------------------------
// Fused QKV, mixed grid 512 (R16).
// ---------------------------------------------------------------------------
__global__ __launch_bounds__(512, 2) void qkv_mix512(
    const u16* __restrict__ Xb, const u16* __restrict__ Wcat,
    u16* __restrict__ Qb, u16* __restrict__ Kb, u16* __restrict__ Vtb)
{
    __shared__ __attribute__((aligned(128))) char LDSRAW[131072];

    int id = blockIdx.x;
    int tid = threadIdx.x, lane = tid & 63, w = tid >> 6;
    int quad = lane >> 4, l15 = lane & 15;
    int wm = w >> 2, wn = w & 3;

    if (id < 256) {
        int ti = (id & 7) * 32 + (id >> 3);
        int bm = ti & 31, bn = ti >> 5;
        int m0 = bm * 256, chb = bn * 256;

        f32x4 acc[8][4];
        const f32x4 z4 = {0.f, 0.f, 0.f, 0.f};
#pragma unroll
        for (int i = 0; i < 8; ++i)
#pragma unroll
            for (int j = 0; j < 4; ++j) acc[i][j] = z4;

        qkv256_core(Xb + (size_t)m0 * C_, Wcat + (size_t)chb * C_, LDSRAW, acc);

#pragma unroll
        for (int mi = 0; mi < 8; ++mi) {
            size_t trow = (size_t)(m0 + (mi >> 2) * 128 + wm * 64 + (mi & 3) * 16 + l15) * C_;
#pragma unroll
            for (int nj = 0; nj < 4; ++nj) {
                int colb = chb + (nj >> 1) * 128 + wn * 32 + (nj & 1) * 16 + quad * 4;
                u16* OUT = (colb < 1024) ? Qb : Kb;
                float sc = (colb < 1024) ? Q_SCALE : 1.0f;
                u16x4 v;
#pragma unroll
                for (int rr = 0; rr < 4; ++rr) v[rr] = f32_to_bf16(acc[mi][nj][rr] * sc);
                *(u16x4*)&OUT[trow + (colb & 1023)] = v;
            }
        }
    } else {
        int id2 = id - 256;
        int hw = (id2 & 7) * 32 + (id2 >> 3);
        int vt = hw >> 6;
        int bm = (hw & 63) >> 1, half = hw & 1;
        int m0h = bm * 256 + half * 128;
        int chb = 2048 + vt * 256;

        f32x4 acc[4][4];
        const f32x4 z4 = {0.f, 0.f, 0.f, 0.f};
#pragma unroll
        for (int i = 0; i < 4; ++i)
#pragma unroll
            for (int j = 0; j < 4; ++j) acc[i][j] = z4;

        qkv128v_core(Xb + (size_t)m0h * C_, Wcat + (size_t)chb * C_, LDSRAW, acc);

#pragma unroll
        for (int mi = 0; mi < 4; ++mi) {
            int t0 = m0h + wm * 64 + mi * 16 + quad * 4;
            int b_ = t0 >> 11, tl = t0 & (T_ - 1);
#pragma unroll
            for (int nj = 0; nj < 4; ++nj) {
                int ch = chb + (nj >> 1) * 128 + wn * 32 + (nj & 1) * 16 + l15;
                int h = (ch >> 6) & 15, d = ch & 63;
                u16x4 v;
#pragma unroll
                for (int rr = 0; rr < 4; ++rr) v[rr] = f32_to_bf16(acc[mi][nj][rr]);
                *(u16x4*)&Vtb[((size_t)(b_ * H_ + h) * D_ + d) * T_ + tl] = v;
            }
        }
    }
}

// ---------------------------------------------------------------------------
// proj 2-phase pipelined core with frag-ahead (R15, unchanged).
// ---------------------------------------------------------------------------
#define RD8(CB, KS, FX, FW)                                                      \
    _Pragma("unroll") for (int i_ = 0; i_ < 4; ++i_) {                           \
        FX[i_] = *(const bf16x8*)((CB) + (KS) * 8192  + xoff[i_]);               \
        FW[i_] = *(const bf16x8*)((CB) + (KS) * 16384 + woff[i_]);               \
    }

#define PPH(ISSUE, GATE, FX, FW, ...)                                            \
  {                                                                              \
    ISSUE;                                                                       \
    if ((GATE) == 6)      asm volatile("s_waitcnt vmcnt(6)" ::: "memory");       \
    else if ((GATE) == 3) asm volatile("s_waitcnt vmcnt(3)" ::: "memory");       \
    else if ((GATE) == 0) asm volatile("s_waitcnt vmcnt(0)" ::: "memory");       \
    __builtin_amdgcn_s_barrier();                                                \
    asm volatile("" ::: "memory");                                               \
    __VA_ARGS__;                                                                 \
    __builtin_amdgcn_sched_barrier(0);                                           \
    __builtin_amdgcn_s_setprio(1);                                               \
    _Pragma("unroll") for (int i = 0; i < 4; ++i)                                \
      _Pragma("unroll") for (int j = 0; j < 4; ++j)                              \
        acc[i][j] = __builtin_amdgcn_mfma_f32_16x16x32_bf16(FW[j], FX[i], acc[i][j], 0, 0, 0); \
    __builtin_amdgcn_s_setprio(0);                                               \
    asm volatile("" ::: "memory");                                               \
    __builtin_amdgcn_s_barrier();                                                \
    asm volatile("" ::: "memory");                                               \
  }

__device__ __forceinline__ void gemm8p_core(const u16* __restrict__ Arow,
                                            const u16* __restrict__ Brow,
                                            char* lds, f32x4 (&acc)[4][4])
{
    int tid  = threadIdx.x;
    int lane = tid & 63, w = tid >> 6;
    int quad = lane >> 4, l15 = lane & 15;
    int wm = w >> 2, wn = w & 3;

    int r  = tid >> 2, s4 = tid & 3;
    int kg = ((s4 - (r >> 1)) & 3) * 8;
    const u16* xsrc  = Arow + (size_t)r * C_ + kg;
    const u16* wsrc0 = Brow + (size_t)r * C_ + kg;
    const u16* wsrc1 = Brow + (size_t)(128 + r) * C_ + kg;
    int wu = w << 10;

    int xoff[4], woff[4];
#pragma unroll
    for (int i = 0; i < 4; ++i) {
        int rx = wm * 64 + i * 16 + l15;
        xoff[i] = rx * 64 + (((rx >> 1) + quad) & 3) * 16;
        int rw = wn * 64 + i * 16 + l15;
        woff[i] = 16384 + rw * 64 + (((rw >> 1) + quad) & 3) * 16;
    }

    auto issue_group = [&](int g) {
        int db = (g >> 1) & 1, ks = g & 1;
        int koff = (g >> 1) * 64 + ks * 32;
        char* ldb = lds + db * 49152;
        async16(xsrc  + koff, ldb + ks * 8192 + wu);
        async16(wsrc0 + koff, ldb + 16384 + ks * 16384 + wu);
        async16(wsrc1 + koff, ldb + 16384 + ks * 16384 + 8192 + wu);
    };

    bf16x8 fAx[4], fAw[4], fBx[4], fBw[4];

    issue_group(0); issue_group(1); issue_group(2);
    asm volatile("s_waitcnt vmcnt(6)" ::: "memory");
    __builtin_amdgcn_s_barrier();
    asm volatile("" ::: "memory");
    RD8(lds, 0, fAx, fAw);

    for (int t = 0; t < NT_ - 1; ++t) {
        char* cb  = lds + (t & 1) * 49152;
        char* cbn = lds + ((t + 1) & 1) * 49152;
        PPH({ issue_group(2 * t + 3); }, 6, fAx, fAw, { RD8(cb, 1, fBx, fBw); });
        if (t < NT_ - 2) {
            PPH({ issue_group(2 * t + 4); }, 6, fBx, fBw, { RD8(cbn, 0, fAx, fAw); });
        } else {
            PPH({}, 3, fBx, fBw, { RD8(cbn, 0, fAx, fAw); });
        }
    }
    {
        char* cb = lds + ((NT_ - 1) & 1) * 49152;
        PPH({}, 0, fAx, fAw, { RD8(cb, 1, fBx, fBw); });
        PPH({}, -1, fBx, fBw, {});
    }
}

// ---------------------------------------------------------------------------
// Flash attention (causal), two-pass R16 structure + T5 setprio.
// Block (jj,bh): pass qt=jj then qt=31-jj (33 staged tiles, uniform).
// S^T/O^T, max-free softmax (raw exp2), register-resident P, l via
// ones-MFMA.  4 blocks/CU (LDS 32KB, launch_bounds(256,4)).
// ---------------------------------------------------------------------------
__global__ __launch_bounds__(256, 4) void attn_kernel(
    const u16* __restrict__ Qb, const u16* __restrict__ Kb,
    const u16* __restrict__ Vtb, u16* __restrict__ Yb)
{
    __shared__ u16 SMA[16384];       // Ks0|Ks1|Vs0|Vs1 (4x8KB), reused by epilogue
    u16* Ks0 = SMA;
    u16* Ks1 = SMA + 4096;
    u16* Vs0 = SMA + 8192;
    u16* Vs1 = SMA + 12288;

    int id = blockIdx.x;
    int bh = id & 63;
    int jj = id >> 6;                // 0..15

    int tid = threadIdx.x, lane = tid & 63, w = tid >> 6;
    int quad = lane >> 4, l15 = lane & 15;
    int b = bh >> 4, h = bh & 15;

    int koff0[4], koff1[4], voff[4][4];
#pragma unroll
    for (int sblk = 0; sblk < 4; ++sblk) {
        int sr = sblk * 16 + l15;
        koff0[sblk] = (sr * 64 + ((quad + sr) & 7) * 8) * 2;
        koff1[sblk] = (sr * 64 + ((4 + quad + sr) & 7) * 8) * 2;
    }
#pragma unroll
    for (int n = 0; n < 4; ++n)
#pragma unroll
        for (int sblk = 0; sblk < 4; ++sblk) {
            int dr = n * 16 + l15;
            voff[n][sblk] = (dr * 64 + ((sblk * 2 + (quad >> 1) + dr) & 7) * 8 + (quad & 1) * 4) * 2;
        }

    int cA = tid, cB = tid + 256;
    int sA = cA >> 3, sB = cB >> 3;
    int offA = (((cA & 7) - sA) & 7) * 8;
    int offB = (((cB & 7) - sB) & 7) * 8;
    const u16* Kbase = Kb + (size_t)(b * T_) * C_ + h * 64;
    const u16* Vbase = Vtb + (size_t)bh * D_ * T_;
    int ldsb0 = (w * 64) * 16, ldsb1 = (256 + w * 64) * 16;

    const s16x4 ones = { (short)0x3F80, (short)0x3F80, (short)0x3F80, (short)0x3F80 };
    const f32x4 z4 = {0.f, 0.f, 0.f, 0.f};

    int qts[2] = { jj, 31 - jj };

    for (int pass = 0; pass < 2; ++pass) {
        int qt = qts[pass];
        int qbase = qt * 64;

        if (pass) __syncthreads();   // prior epilogue LDS reads done

        bf16x8 qf0, qf1;
        {
            const u16* q0 = Qb + ((size_t)(b * T_ + qbase + w * 16 + l15)) * C_ + h * 64;
            qf0 = *(const bf16x8*)(q0 + quad * 8);
            qf1 = *(const bf16x8*)(q0 + 32 + quad * 8);
        }

        f32x4 o_acc[4];
        f32x4 l_acc = z4;
#pragma unroll
        for (int n = 0; n < 4; ++n) o_acc[n] = z4;

        const int nst = qt + 1;

        const u16* kgpA = Kbase + (size_t)sA * C_ + offA;
        const u16* kgpB = Kbase + (size_t)sB * C_ + offB;
        const u16* vgpA = Vbase + sA * T_ + offA;
        const u16* vgpB = Vbase + sB * T_ + offB;

        async16(kgpA, (char*)Ks0 + ldsb0);
        async16(kgpB, (char*)Ks0 + ldsb1);
        async16(vgpA, (char*)Vs0 + ldsb0);
        async16(vgpB, (char*)Vs0 + ldsb1);
        kgpA += 64 * C_; kgpB += 64 * C_; vgpA += 64; vgpB += 64;

        auto tile_body = [&](int st, const u16* K_, const u16* V_, char* Kpf, char* Vpf) {
            __syncthreads();
            if (st + 1 < nst) {
                async16(kgpA, Kpf + ldsb0);
                async16(kgpB, Kpf + ldsb1);
                async16(vgpA, Vpf + ldsb0);
                async16(vgpB, Vpf + ldsb1);
            }
            kgpA += 64 * C_; kgpB += 64 * C_; vgpA += 64; vgpB += 64;

            f32x4 sv[4];
            __builtin_amdgcn_s_setprio(1);
#pragma unroll
            for (int sblk = 0; sblk < 4; ++sblk) {
                bf16x8 k0 = *(const bf16x8*)((const char*)K_ + koff0[sblk]);
                bf16x8 k1 = *(const bf16x8*)((const char*)K_ + koff1[sblk]);
                f32x4 t0 = __builtin_amdgcn_mfma_f32_16x16x32_bf16(k0, qf0, z4, 0, 0, 0);
                sv[sblk] = __builtin_amdgcn_mfma_f32_16x16x32_bf16(k1, qf1, t0, 0, 0, 0);
            }
            __builtin_amdgcn_s_setprio(0);

            if (st == qt) {
                int tl = w * 16 + l15;
#pragma unroll
                for (int sblk = 0; sblk < 4; ++sblk)
#pragma unroll
                    for (int r = 0; r < 4; ++r)
                        if (sblk * 16 + quad * 4 + r > tl) sv[sblk][r] = -1e30f;
            }

            s16x4 pfrag[4];
#pragma unroll
            for (int sblk = 0; sblk < 4; ++sblk) {
#pragma unroll
                for (int r = 0; r < 4; ++r)
                    sv[sblk][r] = __builtin_amdgcn_exp2f(sv[sblk][r]);
                uint2 pk;
                pk.x = pk_bf16(sv[sblk][0], sv[sblk][1]);
                pk.y = pk_bf16(sv[sblk][2], sv[sblk][3]);
                pfrag[sblk] = *(s16x4*)&pk;
                l_acc = __builtin_amdgcn_mfma_f32_16x16x16bf16_1k(ones, pfrag[sblk], l_acc, 0, 0, 0);
            }

            __builtin_amdgcn_s_setprio(1);
#pragma unroll
            for (int n = 0; n < 4; ++n)
#pragma unroll
                for (int sblk = 0; sblk < 4; ++sblk) {
                    s16x4 va = *(const s16x4*)((const char*)V_ + voff[n][sblk]);
                    o_acc[n] = __builtin_amdgcn_mfma_f32_16x16x16bf16_1k(va, pfrag[sblk], o_acc[n], 0, 0, 0);
                }
            __builtin_amdgcn_s_setprio(0);
        };

        for (int st = 0; st < nst; st += 2) {
            tile_body(st, Ks0, Vs0, (char*)Ks1, (char*)Vs1);
            if (st + 1 < nst)
                tile_body(st + 1, Ks1, Vs1, (char*)Ks0, (char*)Vs0);
        }

        __syncthreads();
        u16* PW = SMA + w * 1152;
        {
            float inv = 1.0f / l_acc[0];
#pragma unroll
            for (int n = 0; n < 4; ++n) {
                uint2 pk;
                pk.x = pk_bf16(o_acc[n][0] * inv, o_acc[n][1] * inv);
                pk.y = pk_bf16(o_acc[n][2] * inv, o_acc[n][3] * inv);
                *(u16x4*)&PW[l15 * 72 + n * 16 + quad * 4] = *(u16x4*)&pk;
            }
        }
        asm volatile("s_waitcnt lgkmcnt(0)" ::: "memory");
#pragma unroll
        for (int st = 0; st < 2; ++st) {
            int tr = st * 8 + (lane >> 3);
            int d8 = (lane & 7) * 8;
            u16x8 v = *(u16x8*)&PW[tr * 72 + d8];
            *(u16x8*)&Yb[(size_t)(b * T_ + qbase + w * 16 + tr) * C_ + h * 64 + d8] = v;
        }
    }
}

// ---------------------------------------------------------------------------
// Output projection on the frag-ahead 2-phase core (unchanged).
// Grid 256 = 8 XCD x 32 = exactly one residency round.
// ---------------------------------------------------------------------------
__global__ __launch_bounds__(512, 2) void proj_gemm8(
    const u16* __restrict__ Yb, const u16* __restrict__ Wob,
    const float* __restrict__ bo, float* __restrict__ out)
{
    __shared__ __attribute__((aligned(128))) char LDSRAW[98304];

    int id = blockIdx.x;
    int wg = (id & 7) * 32 + (id >> 3);
    int bm = wg >> 2, bn = wg & 3;
    int m0 = bm * 128, n0 = bn * 256;

    f32x4 acc[4][4];
    const f32x4 z4 = {0.f, 0.f, 0.f, 0.f};
#pragma unroll
    for (int i = 0; i < 4; ++i)
#pragma unroll
        for (int j = 0; j < 4; ++j) acc[i][j] = z4;

    gemm8p_core(Yb + (size_t)m0 * C_, Wob + (size_t)n0 * C_, LDSRAW, acc);

    int tid = threadIdx.x, lane = tid & 63, w = tid >> 6;
    int quad = lane >> 4, l15 = lane & 15;
    int wm = w >> 2, wn = w & 3;

#pragma unroll
    for (int j = 0; j < 4; ++j) {
        int ch = n0 + wn * 64 + j * 16 + quad * 4;
        f32x4 bv = *(const f32x4*)&bo[ch];
#pragma unroll
        for (int i = 0; i < 4; ++i) {
            int t = m0 + wm * 64 + i * 16 + l15;
            f32x4 v = acc[i][j] + bv;
            *(f32x4*)&out[(size_t)t * C_ + ch] = v;
        }
    }
}

// ---------------------------------------------------------------------------
// launch
// ---------------------------------------------------------------------------
extern "C" void kernel_launch(void* const* d_in, const int* in_sizes, int n_in,
                              void* d_out, int out_size, void* d_ws, size_t ws_size,
                              hipStream_t stream) {
    const float* X  = (const float*)d_in[0];
    const float* Wq = (const float*)d_in[1];
    const float* Wk = (const float*)d_in[2];
    const float* Wv = (const float*)d_in[3];
    const float* Wo = (const float*)d_in[4];
    const float* bo = (const float*)d_in[5];

    char* ws = (char*)d_ws;
    u16* Xb  = (u16*)(ws);                       // 16 MB  [BT, C] bf16
    u16* Wqb = (u16*)(ws + (16u << 20));         //  2 MB  } contiguous
    u16* Wkb = (u16*)(ws + (18u << 20));         //  2 MB  } [3072,1024]
    u16* Wvb = (u16*)(ws + (20u << 20));         //  2 MB  } Wcat
    u16* Wob = (u16*)(ws + (22u << 20));         //  2 MB
    u16* Qb  = (u16*)(ws + (24u << 20));         // 16 MB  [BT, C] (pre-scaled)
    u16* Kb  = (u16*)(ws + (40u << 20));         // 16 MB  [BT, C]
    u16* Vtb = (u16*)(ws + (56u << 20));         // 16 MB  [B,H,D,T]
    u16* Yb  = (u16*)(ws + (72u << 20));         // 16 MB  [BT, C]

    cast_all_kernel<<<dim3(8192 + 4 * 1024), 256, 0, stream>>>(
        X, Wq, Wk, Wv, Wo, Xb, Wqb, Wkb, Wvb, Wob);

    qkv_mix512<<<dim3(512), 512, 0, stream>>>(Xb, Wqb, Qb, Kb, Vtb);
    attn_kernel<<<dim3(1024), 256, 0, stream>>>(Qb, Kb, Vtb, Yb);
    proj_gemm8<<<dim3(256), 512, 0, stream>>>(Yb, Wob, bo, (float*)d_out);
}